// Round 2
// baseline (3767.978 us; speedup 1.0000x reference)
//
#include <hip/hip_runtime.h>

// ---------------------------------------------------------------------------
// Workspace layout (float offsets). Peak = 50,331,648 floats = 192 MiB.
// Round-1 evidence: kernels ran end-to-end (err 0.18 << absmax_ref 1.48),
// so ws_size >= 192 MiB. Bug was enc_att staging (l = e>>4 -> e>>5), fixed.
// ---------------------------------------------------------------------------

#define EPS 1e-5f

// ===========================================================================
// conv1 (1->32, 3x3 VALID) + maxpool2 on a 32x32 tile.  grid = 4096 tiles.
// out: (4096, 32, 15, 15)
// ===========================================================================
__global__ __launch_bounds__(256) void conv1_pool(
    const float* __restrict__ t, const float* __restrict__ w,
    const float* __restrict__ bias, float* __restrict__ out)
{
    __shared__ float tile[32][33];
    __shared__ float ws9[288];
    __shared__ float bs[32];
    int n = blockIdx.x, tid = threadIdx.x;
    int b = n >> 4, tt = n & 15, ty = tt >> 2, tx = tt & 3;
    const float* tb = t + (long)b * 16384 + ty * 32 * 128 + tx * 32;
    for (int i = tid; i < 1024; i += 256) {
        int r = i >> 5, cc = i & 31;
        tile[r][cc] = tb[r * 128 + cc] * (1.0f / 255.0f);
    }
    for (int i = tid; i < 288; i += 256) ws9[i] = w[i];
    if (tid < 32) bs[tid] = bias[tid];
    __syncthreads();
    for (int o = tid; o < 7200; o += 256) {
        int c = o / 225, p = o - c * 225;
        int py = p / 15, px = p - py * 15;
        float in[4][4];
        #pragma unroll
        for (int iy = 0; iy < 4; ++iy) {
            #pragma unroll
            for (int ix = 0; ix < 4; ++ix) in[iy][ix] = tile[py * 2 + iy][px * 2 + ix];
        }
        float b0 = bs[c];
        float a00 = b0, a01 = b0, a10 = b0, a11 = b0;
        const float* wc = &ws9[c * 9];
        #pragma unroll
        for (int ky = 0; ky < 3; ++ky) {
            #pragma unroll
            for (int kx = 0; kx < 3; ++kx) {
                float wv = wc[ky * 3 + kx];
                a00 += in[ky][kx] * wv;     a01 += in[ky][kx + 1] * wv;
                a10 += in[ky + 1][kx] * wv; a11 += in[ky + 1][kx + 1] * wv;
            }
        }
        out[(long)n * 7200 + o] = fmaxf(fmaxf(a00, a01), fmaxf(a10, a11));
    }
}

// ===========================================================================
// conv2 (32->32, 3x3 VALID on 15x15) + maxpool2 -> (4096, 32, 6, 6)
// LDS input tile stored [ci][y][x] with x-stride 16 (float2-aligned windows).
// ===========================================================================
__global__ __launch_bounds__(256) void conv2_pool(
    const float* __restrict__ u1, const float* __restrict__ w,
    const float* __restrict__ bias, float* __restrict__ out)
{
    __shared__ float tile[32 * 240];
    int n = blockIdx.x, tid = threadIdx.x;
    const float* src = u1 + (long)n * 7200;
    for (int i = tid; i < 7200; i += 256) {
        int ci = i / 225, rem = i - ci * 225;
        int y = rem / 15, x = rem - y * 15;
        tile[ci * 240 + y * 16 + x] = src[i];
    }
    __syncthreads();
    int c = tid >> 3, s8 = tid & 7;
    float b = bias[c];
    float acc[5][4];
    #pragma unroll
    for (int q = 0; q < 5; ++q) { acc[q][0] = b; acc[q][1] = b; acc[q][2] = b; acc[q][3] = b; }
    const float* wc_base = w + c * 288;
    for (int ci = 0; ci < 32; ++ci) {
        float wc[9];
        #pragma unroll
        for (int t9 = 0; t9 < 9; ++t9) wc[t9] = wc_base[ci * 9 + t9];
        const float* tbase = &tile[ci * 240];
        #pragma unroll
        for (int q = 0; q < 5; ++q) {
            int p = s8 + q * 8;
            if (p < 36) {
                int py = p / 6, px = p - py * 6;
                const float* t0 = tbase + py * 32 + px * 2;
                float in[4][4];
                #pragma unroll
                for (int iy = 0; iy < 4; ++iy) {
                    float2 v01 = *(const float2*)(t0 + iy * 16);
                    float2 v23 = *(const float2*)(t0 + iy * 16 + 2);
                    in[iy][0] = v01.x; in[iy][1] = v01.y; in[iy][2] = v23.x; in[iy][3] = v23.y;
                }
                #pragma unroll
                for (int ky = 0; ky < 3; ++ky) {
                    #pragma unroll
                    for (int kx = 0; kx < 3; ++kx) {
                        float wv = wc[ky * 3 + kx];
                        acc[q][0] += in[ky][kx] * wv;     acc[q][1] += in[ky][kx + 1] * wv;
                        acc[q][2] += in[ky + 1][kx] * wv; acc[q][3] += in[ky + 1][kx + 1] * wv;
                    }
                }
            }
        }
    }
    #pragma unroll
    for (int q = 0; q < 5; ++q) {
        int p = s8 + q * 8;
        if (p < 36) {
            float m = fmaxf(fmaxf(acc[q][0], acc[q][1]), fmaxf(acc[q][2], acc[q][3]));
            out[(long)n * 1152 + c * 36 + p] = m;
        }
    }
}

// ===========================================================================
// expand: relu( (131072, 36) @ (36, 64)^T + b ) -> (131072, 64)
// 64 rows per block.
// ===========================================================================
__global__ __launch_bounds__(256) void expand_k(
    const float* __restrict__ u2, const float* __restrict__ w,
    const float* __restrict__ bias, float* __restrict__ out)
{
    __shared__ float ws[2304];
    __shared__ float xs[2304];
    __shared__ float bs[64];
    int tid = threadIdx.x;
    long r0 = (long)blockIdx.x * 64;
    const float* src = u2 + r0 * 36;
    for (int i = tid; i < 2304; i += 256) { ws[i] = w[i]; xs[i] = src[i]; }
    if (tid < 64) bs[tid] = bias[tid];
    __syncthreads();
    int row = tid >> 2, qq = tid & 3;
    float x[36];
    #pragma unroll
    for (int k4 = 0; k4 < 36; k4 += 4) *(float4*)&x[k4] = *(const float4*)&xs[row * 36 + k4];
    float res[16];
    #pragma unroll
    for (int eo = 0; eo < 16; ++eo) {
        int e = qq * 16 + eo;
        const float* wr = &ws[e * 36];
        float acc = bs[e];
        #pragma unroll
        for (int k4 = 0; k4 < 36; k4 += 4) {
            float4 wv = *(const float4*)&wr[k4];
            acc += x[k4] * wv.x + x[k4 + 1] * wv.y + x[k4 + 2] * wv.z + x[k4 + 3] * wv.w;
        }
        res[eo] = fmaxf(acc, 0.0f);
    }
    float* orow = out + (r0 + row) * 64 + qq * 16;
    #pragma unroll
    for (int v4 = 0; v4 < 4; ++v4) *(float4*)(orow + v4 * 4) = *(float4*)&res[v4 * 4];
}

// ===========================================================================
// Generic fp32 GEMM: C[m][n] = act( sum_k A[m][k]*B[n][k] + bias[n] )
// A (M,K) row-major lda; B (N,K) row-major ldb (i.e. X @ W^T); C (M,N) ldc.
// blockIdx.z = batch*SPLITK + kchunk. SPLITK>1 -> atomicAdd partials, no bias.
// ===========================================================================
template <int BM, int BN, int BK, int TM, int TN, int ACT, int SPLITK>
__global__ __launch_bounds__(256) void gemm_tn(
    const float* __restrict__ A, const float* __restrict__ B,
    const float* __restrict__ bias, float* __restrict__ C,
    int M, int N, int K, int lda, int ldb, int ldc,
    long sA, long sB, long sBias, long sC)
{
    constexpr int NTX = BN / TN;
    constexpr int KG = BK / 4;
    __shared__ float As[BK][BM + 4];
    __shared__ float Bs[BK][BN + 4];
    int tid = threadIdx.x;
    int tx = tid % NTX, ty = tid / NTX;
    int n0 = blockIdx.x * BN, m0 = blockIdx.y * BM;
    int bz = blockIdx.z;
    int batch = bz / SPLITK, kz = bz - batch * SPLITK;
    int Kc = K / SPLITK;
    int k0 = kz * Kc, k1 = k0 + Kc;
    A += (long)batch * sA; B += (long)batch * sB; C += (long)batch * sC;
    const float* bp = bias ? bias + (long)batch * sBias : nullptr;
    float acc[TM][TN] = {};
    for (int kt = k0; kt < k1; kt += BK) {
        constexpr int A4 = BM * BK / 4;
        #pragma unroll
        for (int e0 = 0; e0 < A4; e0 += 256) {
            int e = e0 + tid;
            int rr = e / KG, kg = (e - rr * KG) * 4;
            int gm = m0 + rr;
            float4 v = make_float4(0.f, 0.f, 0.f, 0.f);
            if (gm < M) v = *(const float4*)(A + (long)gm * lda + kt + kg);
            As[kg + 0][rr] = v.x; As[kg + 1][rr] = v.y; As[kg + 2][rr] = v.z; As[kg + 3][rr] = v.w;
        }
        constexpr int B4 = BN * BK / 4;
        #pragma unroll
        for (int e0 = 0; e0 < B4; e0 += 256) {
            int e = e0 + tid;
            int rr = e / KG, kg = (e - rr * KG) * 4;
            int gn = n0 + rr;
            float4 v = make_float4(0.f, 0.f, 0.f, 0.f);
            if (gn < N) v = *(const float4*)(B + (long)gn * ldb + kt + kg);
            Bs[kg + 0][rr] = v.x; Bs[kg + 1][rr] = v.y; Bs[kg + 2][rr] = v.z; Bs[kg + 3][rr] = v.w;
        }
        __syncthreads();
        #pragma unroll
        for (int k = 0; k < BK; ++k) {
            float a[TM], b[TN];
            #pragma unroll
            for (int i = 0; i < TM; i += 4) *(float4*)&a[i] = *(const float4*)&As[k][ty * TM + i];
            #pragma unroll
            for (int j = 0; j < TN; j += 4) *(float4*)&b[j] = *(const float4*)&Bs[k][tx * TN + j];
            #pragma unroll
            for (int i = 0; i < TM; ++i) {
                #pragma unroll
                for (int j = 0; j < TN; ++j) acc[i][j] += a[i] * b[j];
            }
        }
        __syncthreads();
    }
    #pragma unroll
    for (int i = 0; i < TM; ++i) {
        int gm = m0 + ty * TM + i;
        if (gm < M) {
            #pragma unroll
            for (int j = 0; j < TN; ++j) {
                int gn = n0 + tx * TN + j;
                if (gn < N) {
                    float v = acc[i][j];
                    if (SPLITK > 1) {
                        atomicAdd(&C[(long)gm * ldc + gn], v);
                    } else {
                        if (bp) v += bp[gn];
                        if (ACT == 1) v = fmaxf(v, 0.0f);
                        C[(long)gm * ldc + gn] = v;
                    }
                }
            }
        }
    }
}

// ===========================================================================
// Grouped attention + o-proj + residual + LayerNorm(64).
// One block per (g,b). qkv: (16,32,256,192); u residual: (16,32,256,64).
// ===========================================================================
__global__ __launch_bounds__(256) void gatt_ln(
    const float* __restrict__ qkv, const float* __restrict__ u,
    const float* __restrict__ wo, const float* __restrict__ bo,
    const float* __restrict__ lnw, const float* __restrict__ lnb,
    float* __restrict__ out)
{
    __shared__ float sm[12928];
    float* qs  = sm;            // stride 66, 32 rows  -> [0,2112)
    float* ks  = sm + 2112;     // stride 64           -> [2112,4160)
    float* vs  = sm + 4160;     // stride 64           -> [4160,6208)
    float* wos = sm + 6208;     // stride 68, 64 rows  -> [6208,10560)
    float* os  = sm + 10560;    // stride 68, 32 rows  -> [10560,12736)
    float* psT = sm;            // 32x128 = 4096, overlays qs/ks after scores
    float* bos = sm + 12736;
    float* lws = sm + 12800;
    float* lbs = sm + 12864;
    int gb = blockIdx.x;
    int g = gb >> 8, b = gb & 255;
    int tid = threadIdx.x;

    const float* base = qkv + (long)g * 1572864 + b * 192;
    for (int e = tid; e < 1536; e += 256) {
        int s = e / 48, c4 = (e - s * 48) * 4;
        float4 v = *(const float4*)(base + (long)s * 49152 + c4);
        if (c4 < 64) {
            float* q = &qs[s * 66 + c4];
            q[0] = v.x * 0.25f; q[1] = v.y * 0.25f; q[2] = v.z * 0.25f; q[3] = v.w * 0.25f;
        } else if (c4 < 128) {
            *(float4*)&ks[s * 64 + (c4 - 64)] = v;
        } else {
            *(float4*)&vs[s * 64 + (c4 - 128)] = v;
        }
    }
    const float* wog = wo + g * 4096;
    for (int i = tid; i < 4096; i += 256) wos[(i >> 6) * 68 + (i & 63)] = wog[i];
    if (tid < 64) { bos[tid] = bo[g * 64 + tid]; lws[tid] = lnw[tid]; lbs[tid] = lnb[tid]; }
    __syncthreads();

    // scores: thread -> (h=wave-uniform, qi, half)
    int hr = tid >> 1;
    int h = hr >> 5, qi = hr & 31, half = tid & 1;
    float qreg[16];
    #pragma unroll
    for (int d2 = 0; d2 < 16; d2 += 2)
        *(float2*)&qreg[d2] = *(const float2*)&qs[qi * 66 + h * 16 + d2];
    float sc[16];
    #pragma unroll
    for (int jj = 0; jj < 16; ++jj) {
        int j = half * 16 + jj;
        const float* kr = &ks[j * 64 + h * 16];
        float a = 0.f;
        #pragma unroll
        for (int d4 = 0; d4 < 16; d4 += 4) {
            float4 kv = *(const float4*)&kr[d4];
            a += qreg[d4] * kv.x + qreg[d4 + 1] * kv.y + qreg[d4 + 2] * kv.z + qreg[d4 + 3] * kv.w;
        }
        sc[jj] = a;
    }
    float mx = sc[0];
    #pragma unroll
    for (int jj = 1; jj < 16; ++jj) mx = fmaxf(mx, sc[jj]);
    mx = fmaxf(mx, __shfl_xor(mx, 1));
    float sum = 0.f;
    #pragma unroll
    for (int jj = 0; jj < 16; ++jj) { sc[jj] = __expf(sc[jj] - mx); sum += sc[jj]; }
    sum += __shfl_xor(sum, 1);
    float inv = 1.0f / sum;
    __syncthreads();  // all qs/ks reads complete before psT overlay write
    #pragma unroll
    for (int jj = 0; jj < 16; ++jj)
        psT[(half * 16 + jj) * 128 + h * 32 + qi] = sc[jj] * inv;
    __syncthreads();

    // o = P @ V : thread -> (si, e0)
    int si = tid >> 3, e0 = (tid & 7) * 8;
    int hh = e0 >> 4;
    float oacc[8] = {};
    for (int j = 0; j < 32; ++j) {
        float pj = psT[j * 128 + hh * 32 + si];
        const float* vr = &vs[j * 64 + e0];
        float4 v0 = *(const float4*)&vr[0];
        float4 v1 = *(const float4*)&vr[4];
        oacc[0] += pj * v0.x; oacc[1] += pj * v0.y; oacc[2] += pj * v0.z; oacc[3] += pj * v0.w;
        oacc[4] += pj * v1.x; oacc[5] += pj * v1.y; oacc[6] += pj * v1.z; oacc[7] += pj * v1.w;
    }
    #pragma unroll
    for (int e = 0; e < 8; ++e) os[si * 68 + e0 + e] = oacc[e];
    __syncthreads();

    // o-proj + residual + LN(64): thread -> (si, r8), outputs e2 = r8 + 8q
    int r8 = tid & 7;
    float z[8];
    {
        float accq[8];
        #pragma unroll
        for (int q = 0; q < 8; ++q) accq[q] = bos[r8 + q * 8];
        #pragma unroll 4
        for (int e4 = 0; e4 < 64; e4 += 4) {
            float4 ov = *(const float4*)&os[si * 68 + e4];
            #pragma unroll
            for (int q = 0; q < 8; ++q) {
                float4 wv = *(const float4*)&wos[(r8 + q * 8) * 68 + e4];
                accq[q] += ov.x * wv.x + ov.y * wv.y + ov.z * wv.z + ov.w * wv.w;
            }
        }
        long ubase = (((long)g * 32 + si) * 256 + b) * 64;
        #pragma unroll
        for (int q = 0; q < 8; ++q) z[q] = accq[q] + u[ubase + r8 + q * 8];
    }
    float s1 = 0.f, s2 = 0.f;
    #pragma unroll
    for (int q = 0; q < 8; ++q) { s1 += z[q]; s2 += z[q] * z[q]; }
    #pragma unroll
    for (int off = 1; off < 8; off <<= 1) { s1 += __shfl_xor(s1, off); s2 += __shfl_xor(s2, off); }
    float mu = s1 * 0.015625f;
    float var = s2 * 0.015625f - mu * mu;
    float rstd = rsqrtf(var + EPS);
    long obase = (((long)g * 32 + si) * 256 + b) * 64;
    #pragma unroll
    for (int q = 0; q < 8; ++q) {
        int e2 = r8 + q * 8;
        out[obase + e2] = (z[q] - mu) * rstd * lws[e2] + lbs[e2];
    }
}

// ===========================================================================
// Encoder attention (L=16, h=16, hd=128). One block per (b2,h).
// qkv2: (4096 rows = l*256+b2, 6144). o: (16,256,2048).
// ===========================================================================
__global__ __launch_bounds__(256) void enc_att(
    const float* __restrict__ qkv, float* __restrict__ o)
{
    __shared__ float qs[16 * 132], ks[16 * 132], vs[16 * 132], ps[16 * 17];
    int bh = blockIdx.x;
    int b2 = bh >> 4, h = bh & 15;
    int tid = threadIdx.x;
    const float qscale = 0.08838834764831845f;  // 128^-0.5
    // FIX (round-1 bug): 16 rows x 128 cols = 512 float4s -> 32 float4/row.
    // Was l = e>>4, c4 = (e&15)*4: phantom rows 16..31 + LDS overflow into ks/vs.
    for (int e = tid; e < 512; e += 256) {
        int l = e >> 5, c4 = (e & 31) * 4;
        long rowoff = ((long)l * 256 + b2) * 6144 + h * 128 + c4;
        float4 q = *(const float4*)(qkv + rowoff);
        float4 k = *(const float4*)(qkv + rowoff + 2048);
        float4 v = *(const float4*)(qkv + rowoff + 4096);
        q.x *= qscale; q.y *= qscale; q.z *= qscale; q.w *= qscale;
        *(float4*)&qs[l * 132 + c4] = q;
        *(float4*)&ks[l * 132 + c4] = k;
        *(float4*)&vs[l * 132 + c4] = v;
    }
    __syncthreads();
    int qi = tid >> 4, j = tid & 15;
    float acc = 0.f;
    #pragma unroll
    for (int d = 0; d < 128; d += 4) {
        float4 qv = *(const float4*)&qs[qi * 132 + d];
        float4 kv = *(const float4*)&ks[j * 132 + d];
        acc += qv.x * kv.x + qv.y * kv.y + qv.z * kv.z + qv.w * kv.w;
    }
    float m = acc;
    #pragma unroll
    for (int off = 1; off < 16; off <<= 1) m = fmaxf(m, __shfl_xor(m, off));
    float p = __expf(acc - m);
    float sum = p;
    #pragma unroll
    for (int off = 1; off < 16; off <<= 1) sum += __shfl_xor(sum, off);
    ps[qi * 17 + j] = p / sum;
    __syncthreads();
    float pr[16];
    #pragma unroll
    for (int jj = 0; jj < 16; ++jj) pr[jj] = ps[qi * 17 + jj];
    long obase = ((long)qi * 256 + b2) * 2048 + h * 128;
    #pragma unroll
    for (int qd = 0; qd < 8; ++qd) {
        int d = (tid & 15) + qd * 16;
        float a = 0.f;
        #pragma unroll
        for (int jj = 0; jj < 16; ++jj) a += pr[jj] * vs[jj * 132 + d];
        o[obase + d] = a;
    }
}

// ===========================================================================
// residual + LayerNorm over 2048. One block per row.
// ===========================================================================
__global__ __launch_bounds__(256) void resid_ln(
    const float* __restrict__ y, const float* __restrict__ rsd,
    const float* __restrict__ w, const float* __restrict__ bb,
    float* __restrict__ out)
{
    __shared__ float red[8];
    int tid = threadIdx.x;
    long row = blockIdx.x;
    const float* yr = y + row * 2048;
    const float* rr = rsd + row * 2048;
    float4 a0 = *(const float4*)(yr + tid * 4);
    float4 a1 = *(const float4*)(yr + 1024 + tid * 4);
    float4 r0 = *(const float4*)(rr + tid * 4);
    float4 r1 = *(const float4*)(rr + 1024 + tid * 4);
    float v[8] = { a0.x + r0.x, a0.y + r0.y, a0.z + r0.z, a0.w + r0.w,
                   a1.x + r1.x, a1.y + r1.y, a1.z + r1.z, a1.w + r1.w };
    float s1 = 0.f, s2 = 0.f;
    #pragma unroll
    for (int i = 0; i < 8; ++i) { s1 += v[i]; s2 += v[i] * v[i]; }
    #pragma unroll
    for (int off = 1; off < 64; off <<= 1) { s1 += __shfl_xor(s1, off); s2 += __shfl_xor(s2, off); }
    int wid = tid >> 6, lane = tid & 63;
    if (lane == 0) { red[wid * 2] = s1; red[wid * 2 + 1] = s2; }
    __syncthreads();
    s1 = red[0] + red[2] + red[4] + red[6];
    s2 = red[1] + red[3] + red[5] + red[7];
    float mu = s1 * (1.0f / 2048.0f);
    float var = s2 * (1.0f / 2048.0f) - mu * mu;
    float rstd = rsqrtf(var + EPS);
    float4 w0 = *(const float4*)(w + tid * 4);
    float4 w1 = *(const float4*)(w + 1024 + tid * 4);
    float4 b0 = *(const float4*)(bb + tid * 4);
    float4 b1 = *(const float4*)(bb + 1024 + tid * 4);
    float4 o0, o1;
    o0.x = (v[0] - mu) * rstd * w0.x + b0.x; o0.y = (v[1] - mu) * rstd * w0.y + b0.y;
    o0.z = (v[2] - mu) * rstd * w0.z + b0.z; o0.w = (v[3] - mu) * rstd * w0.w + b0.w;
    o1.x = (v[4] - mu) * rstd * w1.x + b1.x; o1.y = (v[5] - mu) * rstd * w1.y + b1.y;
    o1.z = (v[6] - mu) * rstd * w1.z + b1.z; o1.w = (v[7] - mu) * rstd * w1.w + b1.w;
    *(float4*)(out + row * 2048 + tid * 4) = o0;
    *(float4*)(out + row * 2048 + 1024 + tid * 4) = o1;
}

// f1 epilogue after split-K atomics: x = relu(x + bias[col]); (256,512)
__global__ __launch_bounds__(256) void bias_relu_f1(
    float* __restrict__ x, const float* __restrict__ b)
{
    int i = blockIdx.x * 256 + threadIdx.x;
    float v = x[i] + b[i & 511];
    x[i] = fmaxf(v, 0.0f);
}

// ===========================================================================
extern "C" void kernel_launch(void* const* d_in, const int* in_sizes, int n_in,
                              void* d_out, int out_size, void* d_ws, size_t ws_size,
                              hipStream_t stream)
{
    (void)in_sizes; (void)n_in; (void)out_size; (void)ws_size;
    const float* t        = (const float*)d_in[0];
    const float* conv1_w  = (const float*)d_in[1];
    const float* conv1_b  = (const float*)d_in[2];
    const float* conv2_w  = (const float*)d_in[3];
    const float* conv2_b  = (const float*)d_in[4];
    const float* expand_w = (const float*)d_in[5];
    const float* expand_b = (const float*)d_in[6];
    const float* mha_wqkv = (const float*)d_in[7];
    const float* mha_bqkv = (const float*)d_in[8];
    const float* mha_wo   = (const float*)d_in[9];
    const float* mha_bo   = (const float*)d_in[10];
    const float* ln1_w    = (const float*)d_in[11];
    const float* ln1_b    = (const float*)d_in[12];
    const float* enc_wqkv = (const float*)d_in[13];
    const float* enc_bqkv = (const float*)d_in[14];
    const float* enc_wo   = (const float*)d_in[15];
    const float* enc_bo   = (const float*)d_in[16];
    const float* enc_ln1w = (const float*)d_in[17];
    const float* enc_ln1b = (const float*)d_in[18];
    const float* enc_w1   = (const float*)d_in[19];
    const float* enc_b1   = (const float*)d_in[20];
    const float* enc_w2   = (const float*)d_in[21];
    const float* enc_b2   = (const float*)d_in[22];
    const float* enc_ln2w = (const float*)d_in[23];
    const float* enc_ln2b = (const float*)d_in[24];
    const float* f1_w     = (const float*)d_in[25];
    const float* f1_b     = (const float*)d_in[26];
    const float* f2_w     = (const float*)d_in[27];
    const float* f2_b     = (const float*)d_in[28];
    const float* f3_w     = (const float*)d_in[29];
    const float* f3_b     = (const float*)d_in[30];
    float* out = (float*)d_out;

    float* W = (float*)d_ws;
    // region plan (float offsets); lifetimes verified stage-by-stage:
    float* u1   = W;             // [0,29491200)   conv1 out, dead after conv2
    float* u2   = W + 29491200;  // [29491200,34209792) dead after expand
    float* u    = W;             // [0,8388608)    expand out (alias: u1 dead)
    float* qkvg = W + 8388608;   // [8388608,33554432) grouped qkv
    float* uln  = W + 33554432;  // [33554432,41943040) x, residual for ln1
    float* qkv2 = W;             // [0,25165824)   encoder qkv (u,qkvg dead)
    float* obuf = W + 25165824;  // [25165824,33554432) attention out
    float* ytmp = W + 41943040;  // [41943040,50331648) GEMM out pre-LN
    float* x1   = W;             // [0,8388608)    after ln1 (qkv2 dead)
    float* hbuf = W + 8388608;   // [8388608,16777216) FFN hidden
    float* x2   = W + 16777216;  // [16777216,25165824) after ln2
    float* f1o  = W + 25165824;  // 131072 (obuf dead)
    float* f2o  = W + 25296896;  // 32768

    dim3 blk(256);
    conv1_pool<<<4096, blk, 0, stream>>>(t, conv1_w, conv1_b, u1);
    conv2_pool<<<4096, blk, 0, stream>>>(u1, conv2_w, conv2_b, u2);
    expand_k<<<2048, blk, 0, stream>>>(u2, expand_w, expand_b, u);
    // grouped qkv: per g (8192,64)@(64,192)^T
    gemm_tn<64, 64, 16, 4, 4, 0, 1><<<dim3(3, 128, 16), blk, 0, stream>>>(
        u, mha_wqkv, mha_bqkv, qkvg, 8192, 192, 64, 64, 64, 192,
        524288L, 12288L, 192L, 1572864L);
    gatt_ln<<<4096, blk, 0, stream>>>(qkvg, u, mha_wo, mha_bo, ln1_w, ln1_b, uln);
    // encoder qkv: (4096,2048)@(2048,6144)^T
    gemm_tn<128, 128, 16, 8, 8, 0, 1><<<dim3(48, 32, 1), blk, 0, stream>>>(
        uln, enc_wqkv, enc_bqkv, qkv2, 4096, 6144, 2048, 2048, 2048, 6144, 0, 0, 0, 0);
    enc_att<<<4096, blk, 0, stream>>>(qkv2, obuf);
    // o-proj
    gemm_tn<128, 128, 16, 8, 8, 0, 1><<<dim3(16, 32, 1), blk, 0, stream>>>(
        obuf, enc_wo, enc_bo, ytmp, 4096, 2048, 2048, 2048, 2048, 2048, 0, 0, 0, 0);
    resid_ln<<<4096, blk, 0, stream>>>(ytmp, uln, enc_ln1w, enc_ln1b, x1);
    // FFN
    gemm_tn<128, 128, 16, 8, 8, 1, 1><<<dim3(16, 32, 1), blk, 0, stream>>>(
        x1, enc_w1, enc_b1, hbuf, 4096, 2048, 2048, 2048, 2048, 2048, 0, 0, 0, 0);
    gemm_tn<128, 128, 16, 8, 8, 0, 1><<<dim3(16, 32, 1), blk, 0, stream>>>(
        hbuf, enc_w2, enc_b2, ytmp, 4096, 2048, 2048, 2048, 2048, 2048, 0, 0, 0, 0);
    resid_ln<<<4096, blk, 0, stream>>>(ytmp, x1, enc_ln2w, enc_ln2b, x2);
    // f1: (256,32768)@(32768,512)^T via 64-way split-K atomics
    hipMemsetAsync(f1o, 0, 131072 * sizeof(float), stream);
    gemm_tn<64, 64, 16, 4, 4, 0, 64><<<dim3(8, 4, 64), blk, 0, stream>>>(
        x2, f1_w, nullptr, f1o, 256, 512, 32768, 32768, 32768, 512, 0, 0, 0, 0);
    bias_relu_f1<<<512, blk, 0, stream>>>(f1o, f1_b);
    // f2: (256,512)@(512,128)^T + relu
    gemm_tn<64, 64, 16, 4, 4, 1, 1><<<dim3(2, 4, 1), blk, 0, stream>>>(
        f1o, f2_w, f2_b, f2o, 256, 128, 512, 512, 512, 128, 0, 0, 0, 0);
    // f3: (256,128)@(128,25)^T -> d_out
    gemm_tn<64, 64, 16, 4, 4, 0, 1><<<dim3(1, 4, 1), blk, 0, stream>>>(
        f2o, f3_w, f3_b, out, 256, 25, 128, 128, 128, 25, 0, 0, 0, 0);
}

// Round 4
// 1485.959 us; speedup vs baseline: 2.5357x; 2.5357x over previous
//
#include <hip/hip_runtime.h>

// ---------------------------------------------------------------------------
// Round 4 = round 3 resubmitted verbatim (round 3 was an acquisition timeout;
// no evidence to act on). Encoder GEMM stack (qkv 103GF + o-proj 34GF + FFN
// 69GF) on bf16 MFMA (m97-verified structure). Everything else fp32.
// Workspace re-packed; peak use 46,792,704 floats < 48M (known >= 192 MiB).
// ---------------------------------------------------------------------------

#define EPS 1e-5f

typedef __attribute__((ext_vector_type(8))) short s16x8;
typedef __attribute__((ext_vector_type(4))) float f32x4;

__device__ inline float bf2f(ushort u) {
    union { unsigned u; float f; } x; x.u = ((unsigned)u) << 16; return x.f;
}
__device__ inline ushort f2bf(float f) {
    union { float f; unsigned u; } x; x.f = f;
    unsigned r = x.u + 0x7FFFu + ((x.u >> 16) & 1u);   // RTNE
    return (ushort)(r >> 16);
}
__device__ inline void gload_lds16(const void* g, void* l) {
    __builtin_amdgcn_global_load_lds(
        (const __attribute__((address_space(1))) unsigned int*)g,
        (__attribute__((address_space(3))) unsigned int*)l, 16, 0, 0);
}

// ===========================================================================
// conv1 (1->32, 3x3 VALID) + maxpool2 on a 32x32 tile.  grid = 4096 tiles.
// ===========================================================================
__global__ __launch_bounds__(256) void conv1_pool(
    const float* __restrict__ t, const float* __restrict__ w,
    const float* __restrict__ bias, float* __restrict__ out)
{
    __shared__ float tile[32][33];
    __shared__ float ws9[288];
    __shared__ float bs[32];
    int n = blockIdx.x, tid = threadIdx.x;
    int b = n >> 4, tt = n & 15, ty = tt >> 2, tx = tt & 3;
    const float* tb = t + (long)b * 16384 + ty * 32 * 128 + tx * 32;
    for (int i = tid; i < 1024; i += 256) {
        int r = i >> 5, cc = i & 31;
        tile[r][cc] = tb[r * 128 + cc] * (1.0f / 255.0f);
    }
    for (int i = tid; i < 288; i += 256) ws9[i] = w[i];
    if (tid < 32) bs[tid] = bias[tid];
    __syncthreads();
    for (int o = tid; o < 7200; o += 256) {
        int c = o / 225, p = o - c * 225;
        int py = p / 15, px = p - py * 15;
        float in[4][4];
        #pragma unroll
        for (int iy = 0; iy < 4; ++iy) {
            #pragma unroll
            for (int ix = 0; ix < 4; ++ix) in[iy][ix] = tile[py * 2 + iy][px * 2 + ix];
        }
        float b0 = bs[c];
        float a00 = b0, a01 = b0, a10 = b0, a11 = b0;
        const float* wc = &ws9[c * 9];
        #pragma unroll
        for (int ky = 0; ky < 3; ++ky) {
            #pragma unroll
            for (int kx = 0; kx < 3; ++kx) {
                float wv = wc[ky * 3 + kx];
                a00 += in[ky][kx] * wv;     a01 += in[ky][kx + 1] * wv;
                a10 += in[ky + 1][kx] * wv; a11 += in[ky + 1][kx + 1] * wv;
            }
        }
        out[(long)n * 7200 + o] = fmaxf(fmaxf(a00, a01), fmaxf(a10, a11));
    }
}

// ===========================================================================
// conv2 (32->32, 3x3 VALID on 15x15) + maxpool2 -> (4096, 32, 6, 6)
// ===========================================================================
__global__ __launch_bounds__(256) void conv2_pool(
    const float* __restrict__ u1, const float* __restrict__ w,
    const float* __restrict__ bias, float* __restrict__ out)
{
    __shared__ float tile[32 * 240];
    int n = blockIdx.x, tid = threadIdx.x;
    const float* src = u1 + (long)n * 7200;
    for (int i = tid; i < 7200; i += 256) {
        int ci = i / 225, rem = i - ci * 225;
        int y = rem / 15, x = rem - y * 15;
        tile[ci * 240 + y * 16 + x] = src[i];
    }
    __syncthreads();
    int c = tid >> 3, s8 = tid & 7;
    float b = bias[c];
    float acc[5][4];
    #pragma unroll
    for (int q = 0; q < 5; ++q) { acc[q][0] = b; acc[q][1] = b; acc[q][2] = b; acc[q][3] = b; }
    const float* wc_base = w + c * 288;
    for (int ci = 0; ci < 32; ++ci) {
        float wc[9];
        #pragma unroll
        for (int t9 = 0; t9 < 9; ++t9) wc[t9] = wc_base[ci * 9 + t9];
        const float* tbase = &tile[ci * 240];
        #pragma unroll
        for (int q = 0; q < 5; ++q) {
            int p = s8 + q * 8;
            if (p < 36) {
                int py = p / 6, px = p - py * 6;
                const float* t0 = tbase + py * 32 + px * 2;
                float in[4][4];
                #pragma unroll
                for (int iy = 0; iy < 4; ++iy) {
                    float2 v01 = *(const float2*)(t0 + iy * 16);
                    float2 v23 = *(const float2*)(t0 + iy * 16 + 2);
                    in[iy][0] = v01.x; in[iy][1] = v01.y; in[iy][2] = v23.x; in[iy][3] = v23.y;
                }
                #pragma unroll
                for (int ky = 0; ky < 3; ++ky) {
                    #pragma unroll
                    for (int kx = 0; kx < 3; ++kx) {
                        float wv = wc[ky * 3 + kx];
                        acc[q][0] += in[ky][kx] * wv;     acc[q][1] += in[ky][kx + 1] * wv;
                        acc[q][2] += in[ky + 1][kx] * wv; acc[q][3] += in[ky + 1][kx + 1] * wv;
                    }
                }
            }
        }
    }
    #pragma unroll
    for (int q = 0; q < 5; ++q) {
        int p = s8 + q * 8;
        if (p < 36) {
            float m = fmaxf(fmaxf(acc[q][0], acc[q][1]), fmaxf(acc[q][2], acc[q][3]));
            out[(long)n * 1152 + c * 36 + p] = m;
        }
    }
}

// ===========================================================================
// expand: relu( (131072, 36) @ (36, 64)^T + b ) -> (131072, 64)
// ===========================================================================
__global__ __launch_bounds__(256) void expand_k(
    const float* __restrict__ u2, const float* __restrict__ w,
    const float* __restrict__ bias, float* __restrict__ out)
{
    __shared__ float ws[2304];
    __shared__ float xs[2304];
    __shared__ float bs[64];
    int tid = threadIdx.x;
    long r0 = (long)blockIdx.x * 64;
    const float* src = u2 + r0 * 36;
    for (int i = tid; i < 2304; i += 256) { ws[i] = w[i]; xs[i] = src[i]; }
    if (tid < 64) bs[tid] = bias[tid];
    __syncthreads();
    int row = tid >> 2, qq = tid & 3;
    float x[36];
    #pragma unroll
    for (int k4 = 0; k4 < 36; k4 += 4) *(float4*)&x[k4] = *(const float4*)&xs[row * 36 + k4];
    float res[16];
    #pragma unroll
    for (int eo = 0; eo < 16; ++eo) {
        int e = qq * 16 + eo;
        const float* wr = &ws[e * 36];
        float acc = bs[e];
        #pragma unroll
        for (int k4 = 0; k4 < 36; k4 += 4) {
            float4 wv = *(const float4*)&wr[k4];
            acc += x[k4] * wv.x + x[k4 + 1] * wv.y + x[k4 + 2] * wv.z + x[k4 + 3] * wv.w;
        }
        res[eo] = fmaxf(acc, 0.0f);
    }
    float* orow = out + (r0 + row) * 64 + qq * 16;
    #pragma unroll
    for (int v4 = 0; v4 < 4; ++v4) *(float4*)(orow + v4 * 4) = *(float4*)&res[v4 * 4];
}

// ===========================================================================
// Generic fp32 GEMM (kept for grouped-qkv / f1 / f2 / f3)
// ===========================================================================
template <int BM, int BN, int BK, int TM, int TN, int ACT, int SPLITK>
__global__ __launch_bounds__(256) void gemm_tn(
    const float* __restrict__ A, const float* __restrict__ B,
    const float* __restrict__ bias, float* __restrict__ C,
    int M, int N, int K, int lda, int ldb, int ldc,
    long sA, long sB, long sBias, long sC)
{
    constexpr int NTX = BN / TN;
    constexpr int KG = BK / 4;
    __shared__ float As[BK][BM + 4];
    __shared__ float Bs[BK][BN + 4];
    int tid = threadIdx.x;
    int tx = tid % NTX, ty = tid / NTX;
    int n0 = blockIdx.x * BN, m0 = blockIdx.y * BM;
    int bz = blockIdx.z;
    int batch = bz / SPLITK, kz = bz - batch * SPLITK;
    int Kc = K / SPLITK;
    int k0 = kz * Kc, k1 = k0 + Kc;
    A += (long)batch * sA; B += (long)batch * sB; C += (long)batch * sC;
    const float* bp = bias ? bias + (long)batch * sBias : nullptr;
    float acc[TM][TN] = {};
    for (int kt = k0; kt < k1; kt += BK) {
        constexpr int A4 = BM * BK / 4;
        #pragma unroll
        for (int e0 = 0; e0 < A4; e0 += 256) {
            int e = e0 + tid;
            int rr = e / KG, kg = (e - rr * KG) * 4;
            int gm = m0 + rr;
            float4 v = make_float4(0.f, 0.f, 0.f, 0.f);
            if (gm < M) v = *(const float4*)(A + (long)gm * lda + kt + kg);
            As[kg + 0][rr] = v.x; As[kg + 1][rr] = v.y; As[kg + 2][rr] = v.z; As[kg + 3][rr] = v.w;
        }
        constexpr int B4 = BN * BK / 4;
        #pragma unroll
        for (int e0 = 0; e0 < B4; e0 += 256) {
            int e = e0 + tid;
            int rr = e / KG, kg = (e - rr * KG) * 4;
            int gn = n0 + rr;
            float4 v = make_float4(0.f, 0.f, 0.f, 0.f);
            if (gn < N) v = *(const float4*)(B + (long)gn * ldb + kt + kg);
            Bs[kg + 0][rr] = v.x; Bs[kg + 1][rr] = v.y; Bs[kg + 2][rr] = v.z; Bs[kg + 3][rr] = v.w;
        }
        __syncthreads();
        #pragma unroll
        for (int k = 0; k < BK; ++k) {
            float a[TM], b[TN];
            #pragma unroll
            for (int i = 0; i < TM; i += 4) *(float4*)&a[i] = *(const float4*)&As[k][ty * TM + i];
            #pragma unroll
            for (int j = 0; j < TN; j += 4) *(float4*)&b[j] = *(const float4*)&Bs[k][tx * TN + j];
            #pragma unroll
            for (int i = 0; i < TM; ++i) {
                #pragma unroll
                for (int j = 0; j < TN; ++j) acc[i][j] += a[i] * b[j];
            }
        }
        __syncthreads();
    }
    #pragma unroll
    for (int i = 0; i < TM; ++i) {
        int gm = m0 + ty * TM + i;
        if (gm < M) {
            #pragma unroll
            for (int j = 0; j < TN; ++j) {
                int gn = n0 + tx * TN + j;
                if (gn < N) {
                    float v = acc[i][j];
                    if (SPLITK > 1) {
                        atomicAdd(&C[(long)gm * ldc + gn], v);
                    } else {
                        if (bp) v += bp[gn];
                        if (ACT == 1) v = fmaxf(v, 0.0f);
                        C[(long)gm * ldc + gn] = v;
                    }
                }
            }
        }
    }
}

// ===========================================================================
// bf16 MFMA GEMM (m97 structure): C = act(A @ B^T + bias)
// A (M,K) bf16 row-major, B (N,K) bf16 row-major, C fp32 and/or bf16.
// 128x128 tile, BK=64, 4 waves x (64x64), mfma_f32_16x16x32_bf16.
// Staging: global_load_lds width=16, linear LDS [row][64] bf16.
// OUT_MODE: 0 = fp32 only, 2 = bf16 only.  Requires M%128==0, N%128==0, K%64==0.
// ===========================================================================
template <int ACT, int OUT_MODE>
__global__ __launch_bounds__(256) void gemm_bf16(
    const ushort* __restrict__ A, const ushort* __restrict__ B,
    const float* __restrict__ bias, float* __restrict__ Cf,
    ushort* __restrict__ Cb, int M, int N, int K)
{
    __shared__ __align__(16) ushort As[8192];
    __shared__ __align__(16) ushort Bs[8192];
    int tid = threadIdx.x;
    int wave = tid >> 6, lane = tid & 63;
    int m0 = blockIdx.y * 128, n0 = blockIdx.x * 128;
    // staging: wave w stages rows [w*32, w*32+32) of both tiles;
    // issue i covers 8 rows, lane -> row (lane>>3), 16B at col (lane&7)*8.
    const ushort* ga = A + (long)(m0 + wave * 32 + (lane >> 3)) * K + (lane & 7) * 8;
    const ushort* gb = B + (long)(n0 + wave * 32 + (lane >> 3)) * K + (lane & 7) * 8;
    ushort* la = &As[wave * 2048];   // wave-uniform LDS base (+ lane*16B by HW)
    ushort* lb = &Bs[wave * 2048];
    int wr = wave >> 1, wc = wave & 1;        // 2x2 wave grid of 64x64 sub-tiles
    int fr = lane & 15, ks = (lane >> 4) * 8; // A/B fragment: row/col=lane&15, k=(lane>>4)*8+j
    f32x4 acc[4][4];
    #pragma unroll
    for (int i = 0; i < 4; ++i)
        #pragma unroll
        for (int j = 0; j < 4; ++j) acc[i][j] = (f32x4){0.f, 0.f, 0.f, 0.f};

    for (int kt = 0; kt < K; kt += 64) {
        #pragma unroll
        for (int i = 0; i < 4; ++i) {
            gload_lds16(ga + kt + (long)i * 8 * K, la + i * 512);
            gload_lds16(gb + kt + (long)i * 8 * K, lb + i * 512);
        }
        __syncthreads();   // compiler emits vmcnt(0) drain here (m97 structure)
        #pragma unroll
        for (int kk = 0; kk < 64; kk += 32) {
            s16x8 af[4], bfr[4];
            #pragma unroll
            for (int m = 0; m < 4; ++m)
                af[m] = *(const s16x8*)&As[(wr * 64 + m * 16 + fr) * 64 + kk + ks];
            #pragma unroll
            for (int n = 0; n < 4; ++n)
                bfr[n] = *(const s16x8*)&Bs[(wc * 64 + n * 16 + fr) * 64 + kk + ks];
            #pragma unroll
            for (int m = 0; m < 4; ++m)
                #pragma unroll
                for (int n = 0; n < 4; ++n)
                    acc[m][n] = __builtin_amdgcn_mfma_f32_16x16x32_bf16(
                        af[m], bfr[n], acc[m][n], 0, 0, 0);
        }
        __syncthreads();
    }
    // C/D layout (m89/m91-verified): col = lane&15, row = (lane>>4)*4 + j
    int cr = (lane >> 4) * 4;
    #pragma unroll
    for (int n = 0; n < 4; ++n) {
        int col = n0 + wc * 64 + n * 16 + fr;
        float bv = bias ? bias[col] : 0.f;
        #pragma unroll
        for (int m = 0; m < 4; ++m) {
            #pragma unroll
            for (int j = 0; j < 4; ++j) {
                int row = m0 + wr * 64 + m * 16 + cr + j;
                float v = acc[m][n][j] + bv;
                if (ACT == 1) v = fmaxf(v, 0.f);
                if (OUT_MODE != 2) Cf[(long)row * N + col] = v;
                if (OUT_MODE != 0) Cb[(long)row * N + col] = f2bf(v);
            }
        }
    }
}

// ===========================================================================
// fp32 -> bf16 conversion, 8 elem/thread (n must be multiple of 8)
// ===========================================================================
__global__ __launch_bounds__(256) void f2b_kernel(
    const float* __restrict__ in, ushort* __restrict__ out, int n8)
{
    int i = blockIdx.x * 256 + threadIdx.x;
    if (i >= n8) return;
    long base = (long)i * 8;
    float4 v0 = *(const float4*)(in + base);
    float4 v1 = *(const float4*)(in + base + 4);
    ushort4 a, b;
    a.x = f2bf(v0.x); a.y = f2bf(v0.y); a.z = f2bf(v0.z); a.w = f2bf(v0.w);
    b.x = f2bf(v1.x); b.y = f2bf(v1.y); b.z = f2bf(v1.z); b.w = f2bf(v1.w);
    *(ushort4*)(out + base) = a;
    *(ushort4*)(out + base + 4) = b;
}

// ===========================================================================
// Grouped attention + o-proj + residual + LayerNorm(64).  Output bf16.
// ===========================================================================
__global__ __launch_bounds__(256) void gatt_ln(
    const float* __restrict__ qkv, const float* __restrict__ u,
    const float* __restrict__ wo, const float* __restrict__ bo,
    const float* __restrict__ lnw, const float* __restrict__ lnb,
    ushort* __restrict__ out)
{
    __shared__ float sm[12928];
    float* qs  = sm;
    float* ks  = sm + 2112;
    float* vs  = sm + 4160;
    float* wos = sm + 6208;
    float* os  = sm + 10560;
    float* psT = sm;
    float* bos = sm + 12736;
    float* lws = sm + 12800;
    float* lbs = sm + 12864;
    int gb = blockIdx.x;
    int g = gb >> 8, b = gb & 255;
    int tid = threadIdx.x;

    const float* base = qkv + (long)g * 1572864 + b * 192;
    for (int e = tid; e < 1536; e += 256) {
        int s = e / 48, c4 = (e - s * 48) * 4;
        float4 v = *(const float4*)(base + (long)s * 49152 + c4);
        if (c4 < 64) {
            float* q = &qs[s * 66 + c4];
            q[0] = v.x * 0.25f; q[1] = v.y * 0.25f; q[2] = v.z * 0.25f; q[3] = v.w * 0.25f;
        } else if (c4 < 128) {
            *(float4*)&ks[s * 64 + (c4 - 64)] = v;
        } else {
            *(float4*)&vs[s * 64 + (c4 - 128)] = v;
        }
    }
    const float* wog = wo + g * 4096;
    for (int i = tid; i < 4096; i += 256) wos[(i >> 6) * 68 + (i & 63)] = wog[i];
    if (tid < 64) { bos[tid] = bo[g * 64 + tid]; lws[tid] = lnw[tid]; lbs[tid] = lnb[tid]; }
    __syncthreads();

    int hr = tid >> 1;
    int h = hr >> 5, qi = hr & 31, half = tid & 1;
    float qreg[16];
    #pragma unroll
    for (int d2 = 0; d2 < 16; d2 += 2)
        *(float2*)&qreg[d2] = *(const float2*)&qs[qi * 66 + h * 16 + d2];
    float sc[16];
    #pragma unroll
    for (int jj = 0; jj < 16; ++jj) {
        int j = half * 16 + jj;
        const float* kr = &ks[j * 64 + h * 16];
        float a = 0.f;
        #pragma unroll
        for (int d4 = 0; d4 < 16; d4 += 4) {
            float4 kv = *(const float4*)&kr[d4];
            a += qreg[d4] * kv.x + qreg[d4 + 1] * kv.y + qreg[d4 + 2] * kv.z + qreg[d4 + 3] * kv.w;
        }
        sc[jj] = a;
    }
    float mx = sc[0];
    #pragma unroll
    for (int jj = 1; jj < 16; ++jj) mx = fmaxf(mx, sc[jj]);
    mx = fmaxf(mx, __shfl_xor(mx, 1));
    float sum = 0.f;
    #pragma unroll
    for (int jj = 0; jj < 16; ++jj) { sc[jj] = __expf(sc[jj] - mx); sum += sc[jj]; }
    sum += __shfl_xor(sum, 1);
    float inv = 1.0f / sum;
    __syncthreads();
    #pragma unroll
    for (int jj = 0; jj < 16; ++jj)
        psT[(half * 16 + jj) * 128 + h * 32 + qi] = sc[jj] * inv;
    __syncthreads();

    int si = tid >> 3, e0 = (tid & 7) * 8;
    int hh = e0 >> 4;
    float oacc[8] = {};
    for (int j = 0; j < 32; ++j) {
        float pj = psT[j * 128 + hh * 32 + si];
        const float* vr = &vs[j * 64 + e0];
        float4 v0 = *(const float4*)&vr[0];
        float4 v1 = *(const float4*)&vr[4];
        oacc[0] += pj * v0.x; oacc[1] += pj * v0.y; oacc[2] += pj * v0.z; oacc[3] += pj * v0.w;
        oacc[4] += pj * v1.x; oacc[5] += pj * v1.y; oacc[6] += pj * v1.z; oacc[7] += pj * v1.w;
    }
    #pragma unroll
    for (int e = 0; e < 8; ++e) os[si * 68 + e0 + e] = oacc[e];
    __syncthreads();

    int r8 = tid & 7;
    float z[8];
    {
        float accq[8];
        #pragma unroll
        for (int q = 0; q < 8; ++q) accq[q] = bos[r8 + q * 8];
        #pragma unroll 4
        for (int e4 = 0; e4 < 64; e4 += 4) {
            float4 ov = *(const float4*)&os[si * 68 + e4];
            #pragma unroll
            for (int q = 0; q < 8; ++q) {
                float4 wv = *(const float4*)&wos[(r8 + q * 8) * 68 + e4];
                accq[q] += ov.x * wv.x + ov.y * wv.y + ov.z * wv.z + ov.w * wv.w;
            }
        }
        long ubase = (((long)g * 32 + si) * 256 + b) * 64;
        #pragma unroll
        for (int q = 0; q < 8; ++q) z[q] = accq[q] + u[ubase + r8 + q * 8];
    }
    float s1 = 0.f, s2 = 0.f;
    #pragma unroll
    for (int q = 0; q < 8; ++q) { s1 += z[q]; s2 += z[q] * z[q]; }
    #pragma unroll
    for (int off = 1; off < 8; off <<= 1) { s1 += __shfl_xor(s1, off); s2 += __shfl_xor(s2, off); }
    float mu = s1 * 0.015625f;
    float var = s2 * 0.015625f - mu * mu;
    float rstd = rsqrtf(var + EPS);
    long obase = (((long)g * 32 + si) * 256 + b) * 64;
    #pragma unroll
    for (int q = 0; q < 8; ++q) {
        int e2 = r8 + q * 8;
        out[obase + e2] = f2bf((z[q] - mu) * rstd * lws[e2] + lbs[e2]);
    }
}

// ===========================================================================
// Encoder attention (L=16, h=16, hd=128). fp32 in, bf16 out.
// ===========================================================================
__global__ __launch_bounds__(256) void enc_att(
    const float* __restrict__ qkv, ushort* __restrict__ o)
{
    __shared__ float qs[16 * 132], ks[16 * 132], vs[16 * 132], ps[16 * 17];
    int bh = blockIdx.x;
    int b2 = bh >> 4, h = bh & 15;
    int tid = threadIdx.x;
    const float qscale = 0.08838834764831845f;  // 128^-0.5
    for (int e = tid; e < 512; e += 256) {
        int l = e >> 5, c4 = (e & 31) * 4;
        long rowoff = ((long)l * 256 + b2) * 6144 + h * 128 + c4;
        float4 q = *(const float4*)(qkv + rowoff);
        float4 k = *(const float4*)(qkv + rowoff + 2048);
        float4 v = *(const float4*)(qkv + rowoff + 4096);
        q.x *= qscale; q.y *= qscale; q.z *= qscale; q.w *= qscale;
        *(float4*)&qs[l * 132 + c4] = q;
        *(float4*)&ks[l * 132 + c4] = k;
        *(float4*)&vs[l * 132 + c4] = v;
    }
    __syncthreads();
    int qi = tid >> 4, j = tid & 15;
    float acc = 0.f;
    #pragma unroll
    for (int d = 0; d < 128; d += 4) {
        float4 qv = *(const float4*)&qs[qi * 132 + d];
        float4 kv = *(const float4*)&ks[j * 132 + d];
        acc += qv.x * kv.x + qv.y * kv.y + qv.z * kv.z + qv.w * kv.w;
    }
    float m = acc;
    #pragma unroll
    for (int off = 1; off < 16; off <<= 1) m = fmaxf(m, __shfl_xor(m, off));
    float p = __expf(acc - m);
    float sum = p;
    #pragma unroll
    for (int off = 1; off < 16; off <<= 1) sum += __shfl_xor(sum, off);
    ps[qi * 17 + j] = p / sum;
    __syncthreads();
    float pr[16];
    #pragma unroll
    for (int jj = 0; jj < 16; ++jj) pr[jj] = ps[qi * 17 + jj];
    long obase = ((long)qi * 256 + b2) * 2048 + h * 128;
    #pragma unroll
    for (int qd = 0; qd < 8; ++qd) {
        int d = (tid & 15) + qd * 16;
        float a = 0.f;
        #pragma unroll
        for (int jj = 0; jj < 16; ++jj) a += pr[jj] * vs[jj * 132 + d];
        o[obase + d] = f2bf(a);
    }
}

// ===========================================================================
// residual + LayerNorm over 2048. RSD_BF: residual is bf16. OUT_BF: also
// emit bf16 copy. One block per row.
// ===========================================================================
template <int RSD_BF, int OUT_BF>
__global__ __launch_bounds__(256) void resid_ln(
    const float* __restrict__ y, const void* __restrict__ rsdv,
    const float* __restrict__ w, const float* __restrict__ bb,
    float* __restrict__ out, ushort* __restrict__ outb)
{
    __shared__ float red[8];
    int tid = threadIdx.x;
    long row = blockIdx.x;
    const float* yr = y + row * 2048;
    float4 a0 = *(const float4*)(yr + tid * 4);
    float4 a1 = *(const float4*)(yr + 1024 + tid * 4);
    float r[8];
    if (RSD_BF) {
        const ushort* rr = (const ushort*)rsdv + row * 2048;
        ushort4 u0 = *(const ushort4*)(rr + tid * 4);
        ushort4 u1 = *(const ushort4*)(rr + 1024 + tid * 4);
        r[0] = bf2f(u0.x); r[1] = bf2f(u0.y); r[2] = bf2f(u0.z); r[3] = bf2f(u0.w);
        r[4] = bf2f(u1.x); r[5] = bf2f(u1.y); r[6] = bf2f(u1.z); r[7] = bf2f(u1.w);
    } else {
        const float* rr = (const float*)rsdv + row * 2048;
        float4 r0 = *(const float4*)(rr + tid * 4);
        float4 r1 = *(const float4*)(rr + 1024 + tid * 4);
        r[0] = r0.x; r[1] = r0.y; r[2] = r0.z; r[3] = r0.w;
        r[4] = r1.x; r[5] = r1.y; r[6] = r1.z; r[7] = r1.w;
    }
    float v[8] = { a0.x + r[0], a0.y + r[1], a0.z + r[2], a0.w + r[3],
                   a1.x + r[4], a1.y + r[5], a1.z + r[6], a1.w + r[7] };
    float s1 = 0.f, s2 = 0.f;
    #pragma unroll
    for (int i = 0; i < 8; ++i) { s1 += v[i]; s2 += v[i] * v[i]; }
    #pragma unroll
    for (int off = 1; off < 64; off <<= 1) { s1 += __shfl_xor(s1, off); s2 += __shfl_xor(s2, off); }
    int wid = tid >> 6, lane = tid & 63;
    if (lane == 0) { red[wid * 2] = s1; red[wid * 2 + 1] = s2; }
    __syncthreads();
    s1 = red[0] + red[2] + red[4] + red[6];
    s2 = red[1] + red[3] + red[5] + red[7];
    float mu = s1 * (1.0f / 2048.0f);
    float var = s2 * (1.0f / 2048.0f) - mu * mu;
    float rstd = rsqrtf(var + EPS);
    float4 w0 = *(const float4*)(w + tid * 4);
    float4 w1 = *(const float4*)(w + 1024 + tid * 4);
    float4 b0 = *(const float4*)(bb + tid * 4);
    float4 b1 = *(const float4*)(bb + 1024 + tid * 4);
    float o0[8];
    o0[0] = (v[0] - mu) * rstd * w0.x + b0.x; o0[1] = (v[1] - mu) * rstd * w0.y + b0.y;
    o0[2] = (v[2] - mu) * rstd * w0.z + b0.z; o0[3] = (v[3] - mu) * rstd * w0.w + b0.w;
    o0[4] = (v[4] - mu) * rstd * w1.x + b1.x; o0[5] = (v[5] - mu) * rstd * w1.y + b1.y;
    o0[6] = (v[6] - mu) * rstd * w1.z + b1.z; o0[7] = (v[7] - mu) * rstd * w1.w + b1.w;
    *(float4*)(out + row * 2048 + tid * 4) = *(float4*)&o0[0];
    *(float4*)(out + row * 2048 + 1024 + tid * 4) = *(float4*)&o0[4];
    if (OUT_BF) {
        ushort4 q0, q1;
        q0.x = f2bf(o0[0]); q0.y = f2bf(o0[1]); q0.z = f2bf(o0[2]); q0.w = f2bf(o0[3]);
        q1.x = f2bf(o0[4]); q1.y = f2bf(o0[5]); q1.z = f2bf(o0[6]); q1.w = f2bf(o0[7]);
        *(ushort4*)(outb + row * 2048 + tid * 4) = q0;
        *(ushort4*)(outb + row * 2048 + 1024 + tid * 4) = q1;
    }
}

// f1 epilogue after split-K atomics: x = relu(x + bias[col]); (256,512)
__global__ __launch_bounds__(256) void bias_relu_f1(
    float* __restrict__ x, const float* __restrict__ b)
{
    int i = blockIdx.x * 256 + threadIdx.x;
    float v = x[i] + b[i & 511];
    x[i] = fmaxf(v, 0.0f);
}

// ===========================================================================
extern "C" void kernel_launch(void* const* d_in, const int* in_sizes, int n_in,
                              void* d_out, int out_size, void* d_ws, size_t ws_size,
                              hipStream_t stream)
{
    (void)in_sizes; (void)n_in; (void)out_size; (void)ws_size;
    const float* t        = (const float*)d_in[0];
    const float* conv1_w  = (const float*)d_in[1];
    const float* conv1_b  = (const float*)d_in[2];
    const float* conv2_w  = (const float*)d_in[3];
    const float* conv2_b  = (const float*)d_in[4];
    const float* expand_w = (const float*)d_in[5];
    const float* expand_b = (const float*)d_in[6];
    const float* mha_wqkv = (const float*)d_in[7];
    const float* mha_bqkv = (const float*)d_in[8];
    const float* mha_wo   = (const float*)d_in[9];
    const float* mha_bo   = (const float*)d_in[10];
    const float* ln1_w    = (const float*)d_in[11];
    const float* ln1_b    = (const float*)d_in[12];
    const float* enc_wqkv = (const float*)d_in[13];
    const float* enc_bqkv = (const float*)d_in[14];
    const float* enc_wo   = (const float*)d_in[15];
    const float* enc_bo   = (const float*)d_in[16];
    const float* enc_ln1w = (const float*)d_in[17];
    const float* enc_ln1b = (const float*)d_in[18];
    const float* enc_w1   = (const float*)d_in[19];
    const float* enc_b1   = (const float*)d_in[20];
    const float* enc_w2   = (const float*)d_in[21];
    const float* enc_b2   = (const float*)d_in[22];
    const float* enc_ln2w = (const float*)d_in[23];
    const float* enc_ln2b = (const float*)d_in[24];
    const float* f1_w     = (const float*)d_in[25];
    const float* f1_b     = (const float*)d_in[26];
    const float* f2_w     = (const float*)d_in[27];
    const float* f2_b     = (const float*)d_in[28];
    const float* f3_w     = (const float*)d_in[29];
    const float* f3_b     = (const float*)d_in[30];
    float* out = (float*)d_out;

    float* W = (float*)d_ws;
    // ---- region plan (float offsets), lifetimes verified: ----
    float*  u1     = W;                        // [0,29491200)            c1->c2
    float*  u2     = W + 29491200;             // [29491200,34209792)     c2->ex
    float*  u      = W + 34209792;             // [34209792,42598400)     ex->gatt
    float*  qkvg   = W;                        // [0,25165824)            gq->gatt (u1 dead)
    ushort* uln_b  = (ushort*)(W + 42598400);  // [42598400,46792704)     gatt->ln1
    ushort* wqkv_b = (ushort*)(W);             // [0,6291456)             conv->qkvgemm (qkvg dead)
    ushort* wo_b   = (ushort*)(W + 6291456);   // [6291456,8388608)       conv->oproj
    ushort* w1_b   = (ushort*)(W + 33554432);  // [33554432,35651584)     conv->ffn1 (u2/u dead)
    ushort* w2_b   = (ushort*)(W + 35651584);  // [35651584,37748736)     conv->ffn2
    float*  qkv2   = W + 8388608;              // [8388608,33554432)      qkvgemm->encatt
    ushort* obuf_b = (ushort*)(W + 37748736);  // [37748736,41943040)     encatt->oproj
    float*  ytmp   = W + 8388608;              // [8388608,16777216)      oproj->ln1, ffn2->ln2 (qkv2 dead)
    float*  x1     = W + 16777216;             // [16777216,25165824)     ln1->ln2
    ushort* x1_b   = (ushort*)(W + 25165824);  // [25165824,29360128)     ln1->ffn1
    ushort* hbuf_b = (ushort*)(W + 29360128);  // [29360128,33554432)     ffn1->ffn2
    float*  x2     = W;                        // [0,8388608)             ln2->f1 (weights_b dead)
    float*  f1o    = W + 8388608;              // [8388608,8519680)       f1->f2 (ytmp dead)
    float*  f2o    = W + 8519680;              // [8519680,8552448)

    dim3 blk(256);
    conv1_pool<<<4096, blk, 0, stream>>>(t, conv1_w, conv1_b, u1);
    conv2_pool<<<4096, blk, 0, stream>>>(u1, conv2_w, conv2_b, u2);
    expand_k<<<2048, blk, 0, stream>>>(u2, expand_w, expand_b, u);
    // grouped qkv (fp32): per g (8192,64)@(64,192)^T
    gemm_tn<64, 64, 16, 4, 4, 0, 1><<<dim3(3, 128, 16), blk, 0, stream>>>(
        u, mha_wqkv, mha_bqkv, qkvg, 8192, 192, 64, 64, 64, 192,
        524288L, 12288L, 192L, 1572864L);
    gatt_ln<<<4096, blk, 0, stream>>>(qkvg, u, mha_wo, mha_bo, ln1_w, ln1_b, uln_b);
    // weight conversions (regions qkvg/u dead now)
    f2b_kernel<<<6144, blk, 0, stream>>>(enc_wqkv, wqkv_b, 1572864);
    f2b_kernel<<<2048, blk, 0, stream>>>(enc_wo, wo_b, 524288);
    f2b_kernel<<<2048, blk, 0, stream>>>(enc_w1, w1_b, 524288);
    f2b_kernel<<<2048, blk, 0, stream>>>(enc_w2, w2_b, 524288);
    // encoder qkv (bf16 MFMA): (4096,2048)@(2048,6144)^T -> fp32
    gemm_bf16<0, 0><<<dim3(48, 32), blk, 0, stream>>>(
        uln_b, wqkv_b, enc_bqkv, qkv2, nullptr, 4096, 6144, 2048);
    enc_att<<<4096, blk, 0, stream>>>(qkv2, obuf_b);
    // o-proj (bf16 MFMA) -> fp32
    gemm_bf16<0, 0><<<dim3(16, 32), blk, 0, stream>>>(
        obuf_b, wo_b, enc_bo, ytmp, nullptr, 4096, 2048, 2048);
    resid_ln<1, 1><<<4096, blk, 0, stream>>>(ytmp, uln_b, enc_ln1w, enc_ln1b, x1, x1_b);
    // FFN1 (bf16 MFMA, relu, bf16-only out)
    gemm_bf16<1, 2><<<dim3(16, 32), blk, 0, stream>>>(
        x1_b, w1_b, enc_b1, nullptr, hbuf_b, 4096, 2048, 2048);
    // FFN2 (bf16 MFMA) -> fp32
    gemm_bf16<0, 0><<<dim3(16, 32), blk, 0, stream>>>(
        hbuf_b, w2_b, enc_b2, ytmp, nullptr, 4096, 2048, 2048);
    resid_ln<0, 0><<<4096, blk, 0, stream>>>(ytmp, x1, enc_ln2w, enc_ln2b, x2, nullptr);
    // f1 (fp32): (256,32768)@(32768,512)^T via 64-way split-K atomics
    hipMemsetAsync(f1o, 0, 131072 * sizeof(float), stream);
    gemm_tn<64, 64, 16, 4, 4, 0, 64><<<dim3(8, 4, 64), blk, 0, stream>>>(
        x2, f1_w, nullptr, f1o, 256, 512, 32768, 32768, 32768, 512, 0, 0, 0, 0);
    bias_relu_f1<<<512, blk, 0, stream>>>(f1o, f1_b);
    gemm_tn<64, 64, 16, 4, 4, 1, 1><<<dim3(2, 4, 1), blk, 0, stream>>>(
        f1o, f2_w, f2_b, f2o, 256, 128, 512, 512, 512, 128, 0, 0, 0, 0);
    gemm_tn<64, 64, 16, 4, 4, 0, 1><<<dim3(1, 4, 1), blk, 0, stream>>>(
        f2o, f3_w, f3_b, out, 256, 25, 128, 128, 128, 25, 0, 0, 0, 0);
}

// Round 5
// 1163.875 us; speedup vs baseline: 3.2374x; 1.2767x over previous
//
#include <hip/hip_runtime.h>

// ---------------------------------------------------------------------------
// Round 5: conv2 -> bf16 MFMA implicit GEMM (was 404us LDS-conflict-bound
// fp32; 9.5e7 bank conflicts). Per image: C[144][32] = sum_kz A_kz @ Wk[kz]^T,
// nine K=32 MFMA steps. Chunk-XOR swizzled channel-last LDS tile (write+read
// both swizzled). Weights pre-transposed to wk[kz][oc][ci] bf16 once/launch;
// B-frags read from global (L1). Pool fused via stride-33 LDS buffer.
// Everything else identical to passing round-4 kernel (1486us, absmax 9.8e-4).
// ---------------------------------------------------------------------------

#define EPS 1e-5f

typedef __attribute__((ext_vector_type(8))) short s16x8;
typedef __attribute__((ext_vector_type(4))) float f32x4;

__device__ inline float bf2f(ushort u) {
    union { unsigned u; float f; } x; x.u = ((unsigned)u) << 16; return x.f;
}
__device__ inline ushort f2bf(float f) {
    union { float f; unsigned u; } x; x.f = f;
    unsigned r = x.u + 0x7FFFu + ((x.u >> 16) & 1u);   // RTNE
    return (ushort)(r >> 16);
}
__device__ inline void gload_lds16(const void* g, void* l) {
    __builtin_amdgcn_global_load_lds(
        (const __attribute__((address_space(1))) unsigned int*)g,
        (__attribute__((address_space(3))) unsigned int*)l, 16, 0, 0);
}

// ===========================================================================
// conv1 (1->32, 3x3 VALID) + maxpool2 on a 32x32 tile.  grid = 4096 tiles.
// ===========================================================================
__global__ __launch_bounds__(256) void conv1_pool(
    const float* __restrict__ t, const float* __restrict__ w,
    const float* __restrict__ bias, float* __restrict__ out)
{
    __shared__ float tile[32][33];
    __shared__ float ws9[288];
    __shared__ float bs[32];
    int n = blockIdx.x, tid = threadIdx.x;
    int b = n >> 4, tt = n & 15, ty = tt >> 2, tx = tt & 3;
    const float* tb = t + (long)b * 16384 + ty * 32 * 128 + tx * 32;
    for (int i = tid; i < 1024; i += 256) {
        int r = i >> 5, cc = i & 31;
        tile[r][cc] = tb[r * 128 + cc] * (1.0f / 255.0f);
    }
    for (int i = tid; i < 288; i += 256) ws9[i] = w[i];
    if (tid < 32) bs[tid] = bias[tid];
    __syncthreads();
    for (int o = tid; o < 7200; o += 256) {
        int c = o / 225, p = o - c * 225;
        int py = p / 15, px = p - py * 15;
        float in[4][4];
        #pragma unroll
        for (int iy = 0; iy < 4; ++iy) {
            #pragma unroll
            for (int ix = 0; ix < 4; ++ix) in[iy][ix] = tile[py * 2 + iy][px * 2 + ix];
        }
        float b0 = bs[c];
        float a00 = b0, a01 = b0, a10 = b0, a11 = b0;
        const float* wc = &ws9[c * 9];
        #pragma unroll
        for (int ky = 0; ky < 3; ++ky) {
            #pragma unroll
            for (int kx = 0; kx < 3; ++kx) {
                float wv = wc[ky * 3 + kx];
                a00 += in[ky][kx] * wv;     a01 += in[ky][kx + 1] * wv;
                a10 += in[ky + 1][kx] * wv; a11 += in[ky + 1][kx + 1] * wv;
            }
        }
        out[(long)n * 7200 + o] = fmaxf(fmaxf(a00, a01), fmaxf(a10, a11));
    }
}

// ===========================================================================
// weight prep for conv2 MFMA: w (32oc,32ci,3,3) fp32 -> wk (9kz,32oc,32ci) bf16
// ===========================================================================
__global__ __launch_bounds__(256) void convw_prep(
    const float* __restrict__ w, ushort* __restrict__ wk)
{
    int i = blockIdx.x * 256 + threadIdx.x;   // 9216 elems
    if (i >= 9216) return;
    int kz = i >> 10, rem = i & 1023;          // rem = oc*32+ci
    int oc = rem >> 5, ci = rem & 31;
    wk[i] = f2bf(w[oc * 288 + ci * 9 + kz]);
}

// ===========================================================================
// conv2 (32->32, 3x3 VALID on 15x15) + maxpool2 -> (4096, 32, 6, 6)
// bf16 MFMA implicit GEMM. 2 images/block; wave = (img, oc-half).
// LDS tile: channel-last [r=y*16+x][32ci] bf16, 64B rows, chunk-XOR swizzle
// chunk' = chunk ^ ((r>>1)&3)  (applied on write AND read).
// ===========================================================================
__global__ __launch_bounds__(256) void conv2_mfma(
    const float* __restrict__ u1, const ushort* __restrict__ wk,
    const float* __restrict__ bias, float* __restrict__ u2)
{
    __shared__ __align__(16) ushort tiles[2][7680];   // 2 x 15,360 B (240 rows x 64 B)
    __shared__ float hp[2][2376];                     // 2 x 72 rows x 33 (pad) f32
    int tid = threadIdx.x;
    int wave = tid >> 6, lane = tid & 63;
    int n0 = blockIdx.x * 2;

    // ---- stage: u1[n][ci][15][15] fp32 -> tiles[img][r][ci] bf16, swizzled ----
    for (int u = tid; u < 1800; u += 256) {
        int img = u / 900, v = u - img * 900;
        int ks = v / 225, pos = v - ks * 225;      // ks: ci-chunk of 8
        int y = pos / 15, x = pos - y * 15;
        const float* src = u1 + (long)(n0 + img) * 7200 + (ks * 8) * 225 + pos;
        union { s16x8 v8; ushort us[8]; } pk;
        #pragma unroll
        for (int j = 0; j < 8; ++j) pk.us[j] = f2bf(src[j * 225]);
        int r = y * 16 + x;
        int chunk = ks ^ ((r >> 1) & 3);
        *(s16x8*)((char*)&tiles[img][0] + r * 64 + (chunk << 4)) = pk.v8;
    }
    __syncthreads();

    // ---- MFMA: wave -> (img, nf) ----
    int img = wave >> 1, nf = wave & 1;
    int fr = lane & 15, ks4 = lane >> 4;
    int rb[9];
    #pragma unroll
    for (int m = 0; m < 9; ++m) {
        int pos = m * 16 + fr;
        int py = pos / 12, px = pos - py * 12;
        rb[m] = py * 16 + px;
    }
    f32x4 acc[9];
    #pragma unroll
    for (int m = 0; m < 9; ++m) acc[m] = (f32x4){0.f, 0.f, 0.f, 0.f};
    const char* tbase = (const char*)&tiles[img][0];
    #pragma unroll
    for (int kz = 0; kz < 9; ++kz) {
        int ky = kz / 3, kx = kz - ky * 3;
        s16x8 bf = *(const s16x8*)(wk + kz * 1024 + (nf * 16 + fr) * 32 + ks4 * 8);
        #pragma unroll
        for (int m = 0; m < 9; ++m) {
            int r = rb[m] + ky * 16 + kx;
            s16x8 af = *(const s16x8*)(tbase + r * 64 + ((ks4 ^ ((r >> 1) & 3)) << 4));
            acc[m] = __builtin_amdgcn_mfma_f32_16x16x32_bf16(af, bf, acc[m], 0, 0, 0);
        }
    }

    // ---- horizontal pool from C-frags (col=lane&15 -> oc; row=(lane>>4)*4+j) ----
    int oc = nf * 16 + fr;
    int cr4 = ks4 * 4;
    #pragma unroll
    for (int m = 0; m < 9; ++m) {
        float v01 = fmaxf(acc[m][0], acc[m][1]);
        float v23 = fmaxf(acc[m][2], acc[m][3]);
        int p0 = m * 16 + cr4;                    // multiple of 4
        int py = p0 / 12, px0 = p0 - py * 12;     // px0 in {0,4,8}
        int rowb = py * 6 + (px0 >> 1);
        hp[img][rowb * 33 + oc] = v01;
        hp[img][(rowb + 1) * 33 + oc] = v23;
    }
    __syncthreads();

    // ---- vertical pool + bias + store ----
    for (int u = tid; u < 2304; u += 256) {
        int im = u / 1152, v = u - im * 1152;
        int o = v / 36, opos = v - o * 36;
        int i = opos / 6, jj = opos - i * 6;
        float a = hp[im][((2 * i) * 6 + jj) * 33 + o];
        float b = hp[im][((2 * i + 1) * 6 + jj) * 33 + o];
        u2[(long)(n0 + im) * 1152 + o * 36 + opos] = fmaxf(a, b) + bias[o];
    }
}

// ===========================================================================
// expand: relu( (131072, 36) @ (36, 64)^T + b ) -> (131072, 64)
// ===========================================================================
__global__ __launch_bounds__(256) void expand_k(
    const float* __restrict__ u2, const float* __restrict__ w,
    const float* __restrict__ bias, float* __restrict__ out)
{
    __shared__ float ws[2304];
    __shared__ float xs[2304];
    __shared__ float bs[64];
    int tid = threadIdx.x;
    long r0 = (long)blockIdx.x * 64;
    const float* src = u2 + r0 * 36;
    for (int i = tid; i < 2304; i += 256) { ws[i] = w[i]; xs[i] = src[i]; }
    if (tid < 64) bs[tid] = bias[tid];
    __syncthreads();
    int row = tid >> 2, qq = tid & 3;
    float x[36];
    #pragma unroll
    for (int k4 = 0; k4 < 36; k4 += 4) *(float4*)&x[k4] = *(const float4*)&xs[row * 36 + k4];
    float res[16];
    #pragma unroll
    for (int eo = 0; eo < 16; ++eo) {
        int e = qq * 16 + eo;
        const float* wr = &ws[e * 36];
        float acc = bs[e];
        #pragma unroll
        for (int k4 = 0; k4 < 36; k4 += 4) {
            float4 wv = *(const float4*)&wr[k4];
            acc += x[k4] * wv.x + x[k4 + 1] * wv.y + x[k4 + 2] * wv.z + x[k4 + 3] * wv.w;
        }
        res[eo] = fmaxf(acc, 0.0f);
    }
    float* orow = out + (r0 + row) * 64 + qq * 16;
    #pragma unroll
    for (int v4 = 0; v4 < 4; ++v4) *(float4*)(orow + v4 * 4) = *(float4*)&res[v4 * 4];
}

// ===========================================================================
// Generic fp32 GEMM (kept for grouped-qkv / f1 / f2 / f3)
// ===========================================================================
template <int BM, int BN, int BK, int TM, int TN, int ACT, int SPLITK>
__global__ __launch_bounds__(256) void gemm_tn(
    const float* __restrict__ A, const float* __restrict__ B,
    const float* __restrict__ bias, float* __restrict__ C,
    int M, int N, int K, int lda, int ldb, int ldc,
    long sA, long sB, long sBias, long sC)
{
    constexpr int NTX = BN / TN;
    constexpr int KG = BK / 4;
    __shared__ float As[BK][BM + 4];
    __shared__ float Bs[BK][BN + 4];
    int tid = threadIdx.x;
    int tx = tid % NTX, ty = tid / NTX;
    int n0 = blockIdx.x * BN, m0 = blockIdx.y * BM;
    int bz = blockIdx.z;
    int batch = bz / SPLITK, kz = bz - batch * SPLITK;
    int Kc = K / SPLITK;
    int k0 = kz * Kc, k1 = k0 + Kc;
    A += (long)batch * sA; B += (long)batch * sB; C += (long)batch * sC;
    const float* bp = bias ? bias + (long)batch * sBias : nullptr;
    float acc[TM][TN] = {};
    for (int kt = k0; kt < k1; kt += BK) {
        constexpr int A4 = BM * BK / 4;
        #pragma unroll
        for (int e0 = 0; e0 < A4; e0 += 256) {
            int e = e0 + tid;
            int rr = e / KG, kg = (e - rr * KG) * 4;
            int gm = m0 + rr;
            float4 v = make_float4(0.f, 0.f, 0.f, 0.f);
            if (gm < M) v = *(const float4*)(A + (long)gm * lda + kt + kg);
            As[kg + 0][rr] = v.x; As[kg + 1][rr] = v.y; As[kg + 2][rr] = v.z; As[kg + 3][rr] = v.w;
        }
        constexpr int B4 = BN * BK / 4;
        #pragma unroll
        for (int e0 = 0; e0 < B4; e0 += 256) {
            int e = e0 + tid;
            int rr = e / KG, kg = (e - rr * KG) * 4;
            int gn = n0 + rr;
            float4 v = make_float4(0.f, 0.f, 0.f, 0.f);
            if (gn < N) v = *(const float4*)(B + (long)gn * ldb + kt + kg);
            Bs[kg + 0][rr] = v.x; Bs[kg + 1][rr] = v.y; Bs[kg + 2][rr] = v.z; Bs[kg + 3][rr] = v.w;
        }
        __syncthreads();
        #pragma unroll
        for (int k = 0; k < BK; ++k) {
            float a[TM], b[TN];
            #pragma unroll
            for (int i = 0; i < TM; i += 4) *(float4*)&a[i] = *(const float4*)&As[k][ty * TM + i];
            #pragma unroll
            for (int j = 0; j < TN; j += 4) *(float4*)&b[j] = *(const float4*)&Bs[k][tx * TN + j];
            #pragma unroll
            for (int i = 0; i < TM; ++i) {
                #pragma unroll
                for (int j = 0; j < TN; ++j) acc[i][j] += a[i] * b[j];
            }
        }
        __syncthreads();
    }
    #pragma unroll
    for (int i = 0; i < TM; ++i) {
        int gm = m0 + ty * TM + i;
        if (gm < M) {
            #pragma unroll
            for (int j = 0; j < TN; ++j) {
                int gn = n0 + tx * TN + j;
                if (gn < N) {
                    float v = acc[i][j];
                    if (SPLITK > 1) {
                        atomicAdd(&C[(long)gm * ldc + gn], v);
                    } else {
                        if (bp) v += bp[gn];
                        if (ACT == 1) v = fmaxf(v, 0.0f);
                        C[(long)gm * ldc + gn] = v;
                    }
                }
            }
        }
    }
}

// ===========================================================================
// bf16 MFMA GEMM (m97 structure): C = act(A @ B^T + bias)
// ===========================================================================
template <int ACT, int OUT_MODE>
__global__ __launch_bounds__(256) void gemm_bf16(
    const ushort* __restrict__ A, const ushort* __restrict__ B,
    const float* __restrict__ bias, float* __restrict__ Cf,
    ushort* __restrict__ Cb, int M, int N, int K)
{
    __shared__ __align__(16) ushort As[8192];
    __shared__ __align__(16) ushort Bs[8192];
    int tid = threadIdx.x;
    int wave = tid >> 6, lane = tid & 63;
    int m0 = blockIdx.y * 128, n0 = blockIdx.x * 128;
    const ushort* ga = A + (long)(m0 + wave * 32 + (lane >> 3)) * K + (lane & 7) * 8;
    const ushort* gb = B + (long)(n0 + wave * 32 + (lane >> 3)) * K + (lane & 7) * 8;
    ushort* la = &As[wave * 2048];
    ushort* lb = &Bs[wave * 2048];
    int wr = wave >> 1, wc = wave & 1;
    int fr = lane & 15, ks = (lane >> 4) * 8;
    f32x4 acc[4][4];
    #pragma unroll
    for (int i = 0; i < 4; ++i)
        #pragma unroll
        for (int j = 0; j < 4; ++j) acc[i][j] = (f32x4){0.f, 0.f, 0.f, 0.f};

    for (int kt = 0; kt < K; kt += 64) {
        #pragma unroll
        for (int i = 0; i < 4; ++i) {
            gload_lds16(ga + kt + (long)i * 8 * K, la + i * 512);
            gload_lds16(gb + kt + (long)i * 8 * K, lb + i * 512);
        }
        __syncthreads();
        #pragma unroll
        for (int kk = 0; kk < 64; kk += 32) {
            s16x8 af[4], bfr[4];
            #pragma unroll
            for (int m = 0; m < 4; ++m)
                af[m] = *(const s16x8*)&As[(wr * 64 + m * 16 + fr) * 64 + kk + ks];
            #pragma unroll
            for (int n = 0; n < 4; ++n)
                bfr[n] = *(const s16x8*)&Bs[(wc * 64 + n * 16 + fr) * 64 + kk + ks];
            #pragma unroll
            for (int m = 0; m < 4; ++m)
                #pragma unroll
                for (int n = 0; n < 4; ++n)
                    acc[m][n] = __builtin_amdgcn_mfma_f32_16x16x32_bf16(
                        af[m], bfr[n], acc[m][n], 0, 0, 0);
        }
        __syncthreads();
    }
    int cr = (lane >> 4) * 4;
    #pragma unroll
    for (int n = 0; n < 4; ++n) {
        int col = n0 + wc * 64 + n * 16 + fr;
        float bv = bias ? bias[col] : 0.f;
        #pragma unroll
        for (int m = 0; m < 4; ++m) {
            #pragma unroll
            for (int j = 0; j < 4; ++j) {
                int row = m0 + wr * 64 + m * 16 + cr + j;
                float v = acc[m][n][j] + bv;
                if (ACT == 1) v = fmaxf(v, 0.f);
                if (OUT_MODE != 2) Cf[(long)row * N + col] = v;
                if (OUT_MODE != 0) Cb[(long)row * N + col] = f2bf(v);
            }
        }
    }
}

// ===========================================================================
// fp32 -> bf16 conversion, 8 elem/thread
// ===========================================================================
__global__ __launch_bounds__(256) void f2b_kernel(
    const float* __restrict__ in, ushort* __restrict__ out, int n8)
{
    int i = blockIdx.x * 256 + threadIdx.x;
    if (i >= n8) return;
    long base = (long)i * 8;
    float4 v0 = *(const float4*)(in + base);
    float4 v1 = *(const float4*)(in + base + 4);
    ushort4 a, b;
    a.x = f2bf(v0.x); a.y = f2bf(v0.y); a.z = f2bf(v0.z); a.w = f2bf(v0.w);
    b.x = f2bf(v1.x); b.y = f2bf(v1.y); b.z = f2bf(v1.z); b.w = f2bf(v1.w);
    *(ushort4*)(out + base) = a;
    *(ushort4*)(out + base + 4) = b;
}

// ===========================================================================
// Grouped attention + o-proj + residual + LayerNorm(64).  Output bf16.
// ===========================================================================
__global__ __launch_bounds__(256) void gatt_ln(
    const float* __restrict__ qkv, const float* __restrict__ u,
    const float* __restrict__ wo, const float* __restrict__ bo,
    const float* __restrict__ lnw, const float* __restrict__ lnb,
    ushort* __restrict__ out)
{
    __shared__ float sm[12928];
    float* qs  = sm;
    float* ks  = sm + 2112;
    float* vs  = sm + 4160;
    float* wos = sm + 6208;
    float* os  = sm + 10560;
    float* psT = sm;
    float* bos = sm + 12736;
    float* lws = sm + 12800;
    float* lbs = sm + 12864;
    int gb = blockIdx.x;
    int g = gb >> 8, b = gb & 255;
    int tid = threadIdx.x;

    const float* base = qkv + (long)g * 1572864 + b * 192;
    for (int e = tid; e < 1536; e += 256) {
        int s = e / 48, c4 = (e - s * 48) * 4;
        float4 v = *(const float4*)(base + (long)s * 49152 + c4);
        if (c4 < 64) {
            float* q = &qs[s * 66 + c4];
            q[0] = v.x * 0.25f; q[1] = v.y * 0.25f; q[2] = v.z * 0.25f; q[3] = v.w * 0.25f;
        } else if (c4 < 128) {
            *(float4*)&ks[s * 64 + (c4 - 64)] = v;
        } else {
            *(float4*)&vs[s * 64 + (c4 - 128)] = v;
        }
    }
    const float* wog = wo + g * 4096;
    for (int i = tid; i < 4096; i += 256) wos[(i >> 6) * 68 + (i & 63)] = wog[i];
    if (tid < 64) { bos[tid] = bo[g * 64 + tid]; lws[tid] = lnw[tid]; lbs[tid] = lnb[tid]; }
    __syncthreads();

    int hr = tid >> 1;
    int h = hr >> 5, qi = hr & 31, half = tid & 1;
    float qreg[16];
    #pragma unroll
    for (int d2 = 0; d2 < 16; d2 += 2)
        *(float2*)&qreg[d2] = *(const float2*)&qs[qi * 66 + h * 16 + d2];
    float sc[16];
    #pragma unroll
    for (int jj = 0; jj < 16; ++jj) {
        int j = half * 16 + jj;
        const float* kr = &ks[j * 64 + h * 16];
        float a = 0.f;
        #pragma unroll
        for (int d4 = 0; d4 < 16; d4 += 4) {
            float4 kv = *(const float4*)&kr[d4];
            a += qreg[d4] * kv.x + qreg[d4 + 1] * kv.y + qreg[d4 + 2] * kv.z + qreg[d4 + 3] * kv.w;
        }
        sc[jj] = a;
    }
    float mx = sc[0];
    #pragma unroll
    for (int jj = 1; jj < 16; ++jj) mx = fmaxf(mx, sc[jj]);
    mx = fmaxf(mx, __shfl_xor(mx, 1));
    float sum = 0.f;
    #pragma unroll
    for (int jj = 0; jj < 16; ++jj) { sc[jj] = __expf(sc[jj] - mx); sum += sc[jj]; }
    sum += __shfl_xor(sum, 1);
    float inv = 1.0f / sum;
    __syncthreads();
    #pragma unroll
    for (int jj = 0; jj < 16; ++jj)
        psT[(half * 16 + jj) * 128 + h * 32 + qi] = sc[jj] * inv;
    __syncthreads();

    int si = tid >> 3, e0 = (tid & 7) * 8;
    int hh = e0 >> 4;
    float oacc[8] = {};
    for (int j = 0; j < 32; ++j) {
        float pj = psT[j * 128 + hh * 32 + si];
        const float* vr = &vs[j * 64 + e0];
        float4 v0 = *(const float4*)&vr[0];
        float4 v1 = *(const float4*)&vr[4];
        oacc[0] += pj * v0.x; oacc[1] += pj * v0.y; oacc[2] += pj * v0.z; oacc[3] += pj * v0.w;
        oacc[4] += pj * v1.x; oacc[5] += pj * v1.y; oacc[6] += pj * v1.z; oacc[7] += pj * v1.w;
    }
    #pragma unroll
    for (int e = 0; e < 8; ++e) os[si * 68 + e0 + e] = oacc[e];
    __syncthreads();

    int r8 = tid & 7;
    float z[8];
    {
        float accq[8];
        #pragma unroll
        for (int q = 0; q < 8; ++q) accq[q] = bos[r8 + q * 8];
        #pragma unroll 4
        for (int e4 = 0; e4 < 64; e4 += 4) {
            float4 ov = *(const float4*)&os[si * 68 + e4];
            #pragma unroll
            for (int q = 0; q < 8; ++q) {
                float4 wv = *(const float4*)&wos[(r8 + q * 8) * 68 + e4];
                accq[q] += ov.x * wv.x + ov.y * wv.y + ov.z * wv.z + ov.w * wv.w;
            }
        }
        long ubase = (((long)g * 32 + si) * 256 + b) * 64;
        #pragma unroll
        for (int q = 0; q < 8; ++q) z[q] = accq[q] + u[ubase + r8 + q * 8];
    }
    float s1 = 0.f, s2 = 0.f;
    #pragma unroll
    for (int q = 0; q < 8; ++q) { s1 += z[q]; s2 += z[q] * z[q]; }
    #pragma unroll
    for (int off = 1; off < 8; off <<= 1) { s1 += __shfl_xor(s1, off); s2 += __shfl_xor(s2, off); }
    float mu = s1 * 0.015625f;
    float var = s2 * 0.015625f - mu * mu;
    float rstd = rsqrtf(var + EPS);
    long obase = (((long)g * 32 + si) * 256 + b) * 64;
    #pragma unroll
    for (int q = 0; q < 8; ++q) {
        int e2 = r8 + q * 8;
        out[obase + e2] = f2bf((z[q] - mu) * rstd * lws[e2] + lbs[e2]);
    }
}

// ===========================================================================
// Encoder attention (L=16, h=16, hd=128). fp32 in, bf16 out.
// ===========================================================================
__global__ __launch_bounds__(256) void enc_att(
    const float* __restrict__ qkv, ushort* __restrict__ o)
{
    __shared__ float qs[16 * 132], ks[16 * 132], vs[16 * 132], ps[16 * 17];
    int bh = blockIdx.x;
    int b2 = bh >> 4, h = bh & 15;
    int tid = threadIdx.x;
    const float qscale = 0.08838834764831845f;  // 128^-0.5
    for (int e = tid; e < 512; e += 256) {
        int l = e >> 5, c4 = (e & 31) * 4;
        long rowoff = ((long)l * 256 + b2) * 6144 + h * 128 + c4;
        float4 q = *(const float4*)(qkv + rowoff);
        float4 k = *(const float4*)(qkv + rowoff + 2048);
        float4 v = *(const float4*)(qkv + rowoff + 4096);
        q.x *= qscale; q.y *= qscale; q.z *= qscale; q.w *= qscale;
        *(float4*)&qs[l * 132 + c4] = q;
        *(float4*)&ks[l * 132 + c4] = k;
        *(float4*)&vs[l * 132 + c4] = v;
    }
    __syncthreads();
    int qi = tid >> 4, j = tid & 15;
    float acc = 0.f;
    #pragma unroll
    for (int d = 0; d < 128; d += 4) {
        float4 qv = *(const float4*)&qs[qi * 132 + d];
        float4 kv = *(const float4*)&ks[j * 132 + d];
        acc += qv.x * kv.x + qv.y * kv.y + qv.z * kv.z + qv.w * kv.w;
    }
    float m = acc;
    #pragma unroll
    for (int off = 1; off < 16; off <<= 1) m = fmaxf(m, __shfl_xor(m, off));
    float p = __expf(acc - m);
    float sum = p;
    #pragma unroll
    for (int off = 1; off < 16; off <<= 1) sum += __shfl_xor(sum, off);
    ps[qi * 17 + j] = p / sum;
    __syncthreads();
    float pr[16];
    #pragma unroll
    for (int jj = 0; jj < 16; ++jj) pr[jj] = ps[qi * 17 + jj];
    long obase = ((long)qi * 256 + b2) * 2048 + h * 128;
    #pragma unroll
    for (int qd = 0; qd < 8; ++qd) {
        int d = (tid & 15) + qd * 16;
        float a = 0.f;
        #pragma unroll
        for (int jj = 0; jj < 16; ++jj) a += pr[jj] * vs[jj * 132 + d];
        o[obase + d] = f2bf(a);
    }
}

// ===========================================================================
// residual + LayerNorm over 2048.
// ===========================================================================
template <int RSD_BF, int OUT_BF>
__global__ __launch_bounds__(256) void resid_ln(
    const float* __restrict__ y, const void* __restrict__ rsdv,
    const float* __restrict__ w, const float* __restrict__ bb,
    float* __restrict__ out, ushort* __restrict__ outb)
{
    __shared__ float red[8];
    int tid = threadIdx.x;
    long row = blockIdx.x;
    const float* yr = y + row * 2048;
    float4 a0 = *(const float4*)(yr + tid * 4);
    float4 a1 = *(const float4*)(yr + 1024 + tid * 4);
    float r[8];
    if (RSD_BF) {
        const ushort* rr = (const ushort*)rsdv + row * 2048;
        ushort4 u0 = *(const ushort4*)(rr + tid * 4);
        ushort4 u1 = *(const ushort4*)(rr + 1024 + tid * 4);
        r[0] = bf2f(u0.x); r[1] = bf2f(u0.y); r[2] = bf2f(u0.z); r[3] = bf2f(u0.w);
        r[4] = bf2f(u1.x); r[5] = bf2f(u1.y); r[6] = bf2f(u1.z); r[7] = bf2f(u1.w);
    } else {
        const float* rr = (const float*)rsdv + row * 2048;
        float4 r0 = *(const float4*)(rr + tid * 4);
        float4 r1 = *(const float4*)(rr + 1024 + tid * 4);
        r[0] = r0.x; r[1] = r0.y; r[2] = r0.z; r[3] = r0.w;
        r[4] = r1.x; r[5] = r1.y; r[6] = r1.z; r[7] = r1.w;
    }
    float v[8] = { a0.x + r[0], a0.y + r[1], a0.z + r[2], a0.w + r[3],
                   a1.x + r[4], a1.y + r[5], a1.z + r[6], a1.w + r[7] };
    float s1 = 0.f, s2 = 0.f;
    #pragma unroll
    for (int i = 0; i < 8; ++i) { s1 += v[i]; s2 += v[i] * v[i]; }
    #pragma unroll
    for (int off = 1; off < 64; off <<= 1) { s1 += __shfl_xor(s1, off); s2 += __shfl_xor(s2, off); }
    int wid = tid >> 6, lane = tid & 63;
    if (lane == 0) { red[wid * 2] = s1; red[wid * 2 + 1] = s2; }
    __syncthreads();
    s1 = red[0] + red[2] + red[4] + red[6];
    s2 = red[1] + red[3] + red[5] + red[7];
    float mu = s1 * (1.0f / 2048.0f);
    float var = s2 * (1.0f / 2048.0f) - mu * mu;
    float rstd = rsqrtf(var + EPS);
    float4 w0 = *(const float4*)(w + tid * 4);
    float4 w1 = *(const float4*)(w + 1024 + tid * 4);
    float4 b0 = *(const float4*)(bb + tid * 4);
    float4 b1 = *(const float4*)(bb + 1024 + tid * 4);
    float o0[8];
    o0[0] = (v[0] - mu) * rstd * w0.x + b0.x; o0[1] = (v[1] - mu) * rstd * w0.y + b0.y;
    o0[2] = (v[2] - mu) * rstd * w0.z + b0.z; o0[3] = (v[3] - mu) * rstd * w0.w + b0.w;
    o0[4] = (v[4] - mu) * rstd * w1.x + b1.x; o0[5] = (v[5] - mu) * rstd * w1.y + b1.y;
    o0[6] = (v[6] - mu) * rstd * w1.z + b1.z; o0[7] = (v[7] - mu) * rstd * w1.w + b1.w;
    *(float4*)(out + row * 2048 + tid * 4) = *(float4*)&o0[0];
    *(float4*)(out + row * 2048 + 1024 + tid * 4) = *(float4*)&o0[4];
    if (OUT_BF) {
        ushort4 q0, q1;
        q0.x = f2bf(o0[0]); q0.y = f2bf(o0[1]); q0.z = f2bf(o0[2]); q0.w = f2bf(o0[3]);
        q1.x = f2bf(o0[4]); q1.y = f2bf(o0[5]); q1.z = f2bf(o0[6]); q1.w = f2bf(o0[7]);
        *(ushort4*)(outb + row * 2048 + tid * 4) = q0;
        *(ushort4*)(outb + row * 2048 + 1024 + tid * 4) = q1;
    }
}

// f1 epilogue after split-K atomics: x = relu(x + bias[col]); (256,512)
__global__ __launch_bounds__(256) void bias_relu_f1(
    float* __restrict__ x, const float* __restrict__ b)
{
    int i = blockIdx.x * 256 + threadIdx.x;
    float v = x[i] + b[i & 511];
    x[i] = fmaxf(v, 0.0f);
}

// ===========================================================================
extern "C" void kernel_launch(void* const* d_in, const int* in_sizes, int n_in,
                              void* d_out, int out_size, void* d_ws, size_t ws_size,
                              hipStream_t stream)
{
    (void)in_sizes; (void)n_in; (void)out_size; (void)ws_size;
    const float* t        = (const float*)d_in[0];
    const float* conv1_w  = (const float*)d_in[1];
    const float* conv1_b  = (const float*)d_in[2];
    const float* conv2_w  = (const float*)d_in[3];
    const float* conv2_b  = (const float*)d_in[4];
    const float* expand_w = (const float*)d_in[5];
    const float* expand_b = (const float*)d_in[6];
    const float* mha_wqkv = (const float*)d_in[7];
    const float* mha_bqkv = (const float*)d_in[8];
    const float* mha_wo   = (const float*)d_in[9];
    const float* mha_bo   = (const float*)d_in[10];
    const float* ln1_w    = (const float*)d_in[11];
    const float* ln1_b    = (const float*)d_in[12];
    const float* enc_wqkv = (const float*)d_in[13];
    const float* enc_bqkv = (const float*)d_in[14];
    const float* enc_wo   = (const float*)d_in[15];
    const float* enc_bo   = (const float*)d_in[16];
    const float* enc_ln1w = (const float*)d_in[17];
    const float* enc_ln1b = (const float*)d_in[18];
    const float* enc_w1   = (const float*)d_in[19];
    const float* enc_b1   = (const float*)d_in[20];
    const float* enc_w2   = (const float*)d_in[21];
    const float* enc_b2   = (const float*)d_in[22];
    const float* enc_ln2w = (const float*)d_in[23];
    const float* enc_ln2b = (const float*)d_in[24];
    const float* f1_w     = (const float*)d_in[25];
    const float* f1_b     = (const float*)d_in[26];
    const float* f2_w     = (const float*)d_in[27];
    const float* f2_b     = (const float*)d_in[28];
    const float* f3_w     = (const float*)d_in[29];
    const float* f3_b     = (const float*)d_in[30];
    float* out = (float*)d_out;

    float* W = (float*)d_ws;
    // ---- region plan (float offsets), lifetimes verified: ----
    float*  u1     = W;                        // [0,29491200)            c1->c2
    float*  u2     = W + 29491200;             // [29491200,34209792)     c2->ex
    float*  u      = W + 34209792;             // [34209792,42598400)     ex->gatt
    float*  qkvg   = W;                        // [0,25165824)            gq->gatt (u1 dead)
    ushort* uln_b  = (ushort*)(W + 42598400);  // [42598400,46792704)     gatt->ln1
    ushort* wk     = (ushort*)(W + 46800000);  // [46800000,46804608)     prep->conv2
    ushort* wqkv_b = (ushort*)(W);             // [0,6291456)             conv->qkvgemm (qkvg dead)
    ushort* wo_b   = (ushort*)(W + 6291456);   // [6291456,8388608)       conv->oproj
    ushort* w1_b   = (ushort*)(W + 33554432);  // [33554432,35651584)     conv->ffn1 (u2/u dead)
    ushort* w2_b   = (ushort*)(W + 35651584);  // [35651584,37748736)     conv->ffn2
    float*  qkv2   = W + 8388608;              // [8388608,33554432)      qkvgemm->encatt
    ushort* obuf_b = (ushort*)(W + 37748736);  // [37748736,41943040)     encatt->oproj
    float*  ytmp   = W + 8388608;              // [8388608,16777216)      oproj->ln1, ffn2->ln2 (qkv2 dead)
    float*  x1     = W + 16777216;             // [16777216,25165824)     ln1->ln2
    ushort* x1_b   = (ushort*)(W + 25165824);  // [25165824,29360128)     ln1->ffn1
    ushort* hbuf_b = (ushort*)(W + 29360128);  // [29360128,33554432)     ffn1->ffn2
    float*  x2     = W;                        // [0,8388608)             ln2->f1 (weights_b dead)
    float*  f1o    = W + 8388608;              // [8388608,8519680)       f1->f2 (ytmp dead)
    float*  f2o    = W + 8519680;              // [8519680,8552448)

    dim3 blk(256);
    convw_prep<<<36, blk, 0, stream>>>(conv2_w, wk);
    conv1_pool<<<4096, blk, 0, stream>>>(t, conv1_w, conv1_b, u1);
    conv2_mfma<<<2048, blk, 0, stream>>>(u1, wk, conv2_b, u2);
    expand_k<<<2048, blk, 0, stream>>>(u2, expand_w, expand_b, u);
    // grouped qkv (fp32): per g (8192,64)@(64,192)^T
    gemm_tn<64, 64, 16, 4, 4, 0, 1><<<dim3(3, 128, 16), blk, 0, stream>>>(
        u, mha_wqkv, mha_bqkv, qkvg, 8192, 192, 64, 64, 64, 192,
        524288L, 12288L, 192L, 1572864L);
    gatt_ln<<<4096, blk, 0, stream>>>(qkvg, u, mha_wo, mha_bo, ln1_w, ln1_b, uln_b);
    // weight conversions (regions qkvg/u dead now)
    f2b_kernel<<<6144, blk, 0, stream>>>(enc_wqkv, wqkv_b, 1572864);
    f2b_kernel<<<2048, blk, 0, stream>>>(enc_wo, wo_b, 524288);
    f2b_kernel<<<2048, blk, 0, stream>>>(enc_w1, w1_b, 524288);
    f2b_kernel<<<2048, blk, 0, stream>>>(enc_w2, w2_b, 524288);
    // encoder qkv (bf16 MFMA): (4096,2048)@(2048,6144)^T -> fp32
    gemm_bf16<0, 0><<<dim3(48, 32), blk, 0, stream>>>(
        uln_b, wqkv_b, enc_bqkv, qkv2, nullptr, 4096, 6144, 2048);
    enc_att<<<4096, blk, 0, stream>>>(qkv2, obuf_b);
    // o-proj (bf16 MFMA) -> fp32
    gemm_bf16<0, 0><<<dim3(16, 32), blk, 0, stream>>>(
        obuf_b, wo_b, enc_bo, ytmp, nullptr, 4096, 2048, 2048);
    resid_ln<1, 1><<<4096, blk, 0, stream>>>(ytmp, uln_b, enc_ln1w, enc_ln1b, x1, x1_b);
    // FFN1 (bf16 MFMA, relu, bf16-only out)
    gemm_bf16<1, 2><<<dim3(16, 32), blk, 0, stream>>>(
        x1_b, w1_b, enc_b1, nullptr, hbuf_b, 4096, 2048, 2048);
    // FFN2 (bf16 MFMA) -> fp32
    gemm_bf16<0, 0><<<dim3(16, 32), blk, 0, stream>>>(
        hbuf_b, w2_b, enc_b2, ytmp, nullptr, 4096, 2048, 2048);
    resid_ln<0, 0><<<4096, blk, 0, stream>>>(ytmp, x1, enc_ln2w, enc_ln2b, x2, nullptr);
    // f1 (fp32): (256,32768)@(32768,512)^T via 64-way split-K atomics
    hipMemsetAsync(f1o, 0, 131072 * sizeof(float), stream);
    gemm_tn<64, 64, 16, 4, 4, 0, 64><<<dim3(8, 4, 64), blk, 0, stream>>>(
        x2, f1_w, nullptr, f1o, 256, 512, 32768, 32768, 32768, 512, 0, 0, 0, 0);
    bias_relu_f1<<<512, blk, 0, stream>>>(f1o, f1_b);
    gemm_tn<64, 64, 16, 4, 4, 1, 1><<<dim3(2, 4, 1), blk, 0, stream>>>(
        f1o, f2_w, f2_b, f2o, 256, 128, 512, 512, 512, 128, 0, 0, 0, 0);
    gemm_tn<64, 64, 16, 4, 4, 0, 1><<<dim3(1, 4, 1), blk, 0, stream>>>(
        f2o, f3_w, f3_b, out, 256, 25, 128, 128, 128, 25, 0, 0, 0, 0);
}

// Round 8
// 1004.563 us; speedup vs baseline: 3.7509x; 1.1586x over previous
//
#include <hip/hip_runtime.h>

// ---------------------------------------------------------------------------
// Round 8 = round 6 resubmitted verbatim (rounds 6 and 7 were acquisition
// timeouts; no evidence to act on). Changes vs round-5 (1164us, absmax 2e-3):
// (a) f1 split-K atomics (187us, WRITE=128MiB atomic fabric traffic)
// -> bf16 MFMA split-K=64 partials + reduce kernel, zero atomics.
// (b) conv1 emits bf16 u1 (conv2 converted to bf16 at staging anyway) —
// halves conv1-write/conv2-read traffic, identical arithmetic.
// ---------------------------------------------------------------------------

#define EPS 1e-5f

typedef __attribute__((ext_vector_type(8))) short s16x8;
typedef __attribute__((ext_vector_type(4))) float f32x4;

__device__ inline float bf2f(ushort u) {
    union { unsigned u; float f; } x; x.u = ((unsigned)u) << 16; return x.f;
}
__device__ inline ushort f2bf(float f) {
    union { float f; unsigned u; } x; x.f = f;
    unsigned r = x.u + 0x7FFFu + ((x.u >> 16) & 1u);   // RTNE
    return (ushort)(r >> 16);
}
__device__ inline void gload_lds16(const void* g, void* l) {
    __builtin_amdgcn_global_load_lds(
        (const __attribute__((address_space(1))) unsigned int*)g,
        (__attribute__((address_space(3))) unsigned int*)l, 16, 0, 0);
}

// ===========================================================================
// conv1 (1->32, 3x3 VALID) + maxpool2 on a 32x32 tile. Output bf16.
// ===========================================================================
__global__ __launch_bounds__(256) void conv1_pool(
    const float* __restrict__ t, const float* __restrict__ w,
    const float* __restrict__ bias, ushort* __restrict__ out)
{
    __shared__ float tile[32][33];
    __shared__ float ws9[288];
    __shared__ float bs[32];
    int n = blockIdx.x, tid = threadIdx.x;
    int b = n >> 4, tt = n & 15, ty = tt >> 2, tx = tt & 3;
    const float* tb = t + (long)b * 16384 + ty * 32 * 128 + tx * 32;
    for (int i = tid; i < 1024; i += 256) {
        int r = i >> 5, cc = i & 31;
        tile[r][cc] = tb[r * 128 + cc] * (1.0f / 255.0f);
    }
    for (int i = tid; i < 288; i += 256) ws9[i] = w[i];
    if (tid < 32) bs[tid] = bias[tid];
    __syncthreads();
    for (int o = tid; o < 7200; o += 256) {
        int c = o / 225, p = o - c * 225;
        int py = p / 15, px = p - py * 15;
        float in[4][4];
        #pragma unroll
        for (int iy = 0; iy < 4; ++iy) {
            #pragma unroll
            for (int ix = 0; ix < 4; ++ix) in[iy][ix] = tile[py * 2 + iy][px * 2 + ix];
        }
        float b0 = bs[c];
        float a00 = b0, a01 = b0, a10 = b0, a11 = b0;
        const float* wc = &ws9[c * 9];
        #pragma unroll
        for (int ky = 0; ky < 3; ++ky) {
            #pragma unroll
            for (int kx = 0; kx < 3; ++kx) {
                float wv = wc[ky * 3 + kx];
                a00 += in[ky][kx] * wv;     a01 += in[ky][kx + 1] * wv;
                a10 += in[ky + 1][kx] * wv; a11 += in[ky + 1][kx + 1] * wv;
            }
        }
        out[(long)n * 7200 + o] = f2bf(fmaxf(fmaxf(a00, a01), fmaxf(a10, a11)));
    }
}

// ===========================================================================
// weight prep for conv2 MFMA: w (32oc,32ci,3,3) fp32 -> wk (9kz,32oc,32ci) bf16
// ===========================================================================
__global__ __launch_bounds__(256) void convw_prep(
    const float* __restrict__ w, ushort* __restrict__ wk)
{
    int i = blockIdx.x * 256 + threadIdx.x;   // 9216 elems
    if (i >= 9216) return;
    int kz = i >> 10, rem = i & 1023;          // rem = oc*32+ci
    int oc = rem >> 5, ci = rem & 31;
    wk[i] = f2bf(w[oc * 288 + ci * 9 + kz]);
}

// ===========================================================================
// conv2 (32->32, 3x3 VALID on 15x15) + maxpool2 -> (4096, 32, 6, 6)
// bf16 MFMA implicit GEMM. u1 input bf16.
// ===========================================================================
__global__ __launch_bounds__(256) void conv2_mfma(
    const ushort* __restrict__ u1, const ushort* __restrict__ wk,
    const float* __restrict__ bias, float* __restrict__ u2)
{
    __shared__ __align__(16) ushort tiles[2][7680];   // 2 x 15,360 B (240 rows x 64 B)
    __shared__ float hp[2][2376];                     // 2 x 72 rows x 33 (pad) f32
    int tid = threadIdx.x;
    int wave = tid >> 6, lane = tid & 63;
    int n0 = blockIdx.x * 2;

    // ---- stage: u1[n][ci][15][15] bf16 -> tiles[img][r][ci], swizzled ----
    for (int u = tid; u < 1800; u += 256) {
        int img = u / 900, v = u - img * 900;
        int ks = v / 225, pos = v - ks * 225;      // ks: ci-chunk of 8
        int y = pos / 15, x = pos - y * 15;
        const ushort* src = u1 + (long)(n0 + img) * 7200 + (ks * 8) * 225 + pos;
        union { s16x8 v8; ushort us[8]; } pk;
        #pragma unroll
        for (int j = 0; j < 8; ++j) pk.us[j] = src[j * 225];
        int r = y * 16 + x;
        int chunk = ks ^ ((r >> 1) & 3);
        *(s16x8*)((char*)&tiles[img][0] + r * 64 + (chunk << 4)) = pk.v8;
    }
    __syncthreads();

    // ---- MFMA: wave -> (img, nf) ----
    int img = wave >> 1, nf = wave & 1;
    int fr = lane & 15, ks4 = lane >> 4;
    int rb[9];
    #pragma unroll
    for (int m = 0; m < 9; ++m) {
        int pos = m * 16 + fr;
        int py = pos / 12, px = pos - py * 12;
        rb[m] = py * 16 + px;
    }
    f32x4 acc[9];
    #pragma unroll
    for (int m = 0; m < 9; ++m) acc[m] = (f32x4){0.f, 0.f, 0.f, 0.f};
    const char* tbase = (const char*)&tiles[img][0];
    #pragma unroll
    for (int kz = 0; kz < 9; ++kz) {
        int ky = kz / 3, kx = kz - ky * 3;
        s16x8 bf = *(const s16x8*)(wk + kz * 1024 + (nf * 16 + fr) * 32 + ks4 * 8);
        #pragma unroll
        for (int m = 0; m < 9; ++m) {
            int r = rb[m] + ky * 16 + kx;
            s16x8 af = *(const s16x8*)(tbase + r * 64 + ((ks4 ^ ((r >> 1) & 3)) << 4));
            acc[m] = __builtin_amdgcn_mfma_f32_16x16x32_bf16(af, bf, acc[m], 0, 0, 0);
        }
    }

    // ---- horizontal pool from C-frags (col=lane&15 -> oc; row=(lane>>4)*4+j) ----
    int oc = nf * 16 + fr;
    int cr4 = ks4 * 4;
    #pragma unroll
    for (int m = 0; m < 9; ++m) {
        float v01 = fmaxf(acc[m][0], acc[m][1]);
        float v23 = fmaxf(acc[m][2], acc[m][3]);
        int p0 = m * 16 + cr4;                    // multiple of 4
        int py = p0 / 12, px0 = p0 - py * 12;     // px0 in {0,4,8}
        int rowb = py * 6 + (px0 >> 1);
        hp[img][rowb * 33 + oc] = v01;
        hp[img][(rowb + 1) * 33 + oc] = v23;
    }
    __syncthreads();

    // ---- vertical pool + bias + store ----
    for (int u = tid; u < 2304; u += 256) {
        int im = u / 1152, v = u - im * 1152;
        int o = v / 36, opos = v - o * 36;
        int i = opos / 6, jj = opos - i * 6;
        float a = hp[im][((2 * i) * 6 + jj) * 33 + o];
        float b = hp[im][((2 * i + 1) * 6 + jj) * 33 + o];
        u2[(long)(n0 + im) * 1152 + o * 36 + opos] = fmaxf(a, b) + bias[o];
    }
}

// ===========================================================================
// expand: relu( (131072, 36) @ (36, 64)^T + b ) -> (131072, 64)
// ===========================================================================
__global__ __launch_bounds__(256) void expand_k(
    const float* __restrict__ u2, const float* __restrict__ w,
    const float* __restrict__ bias, float* __restrict__ out)
{
    __shared__ float ws[2304];
    __shared__ float xs[2304];
    __shared__ float bs[64];
    int tid = threadIdx.x;
    long r0 = (long)blockIdx.x * 64;
    const float* src = u2 + r0 * 36;
    for (int i = tid; i < 2304; i += 256) { ws[i] = w[i]; xs[i] = src[i]; }
    if (tid < 64) bs[tid] = bias[tid];
    __syncthreads();
    int row = tid >> 2, qq = tid & 3;
    float x[36];
    #pragma unroll
    for (int k4 = 0; k4 < 36; k4 += 4) *(float4*)&x[k4] = *(const float4*)&xs[row * 36 + k4];
    float res[16];
    #pragma unroll
    for (int eo = 0; eo < 16; ++eo) {
        int e = qq * 16 + eo;
        const float* wr = &ws[e * 36];
        float acc = bs[e];
        #pragma unroll
        for (int k4 = 0; k4 < 36; k4 += 4) {
            float4 wv = *(const float4*)&wr[k4];
            acc += x[k4] * wv.x + x[k4 + 1] * wv.y + x[k4 + 2] * wv.z + x[k4 + 3] * wv.w;
        }
        res[eo] = fmaxf(acc, 0.0f);
    }
    float* orow = out + (r0 + row) * 64 + qq * 16;
    #pragma unroll
    for (int v4 = 0; v4 < 4; ++v4) *(float4*)(orow + v4 * 4) = *(float4*)&res[v4 * 4];
}

// ===========================================================================
// Generic fp32 GEMM (kept for grouped-qkv / f2 / f3)
// ===========================================================================
template <int BM, int BN, int BK, int TM, int TN, int ACT, int SPLITK>
__global__ __launch_bounds__(256) void gemm_tn(
    const float* __restrict__ A, const float* __restrict__ B,
    const float* __restrict__ bias, float* __restrict__ C,
    int M, int N, int K, int lda, int ldb, int ldc,
    long sA, long sB, long sBias, long sC)
{
    constexpr int NTX = BN / TN;
    constexpr int KG = BK / 4;
    __shared__ float As[BK][BM + 4];
    __shared__ float Bs[BK][BN + 4];
    int tid = threadIdx.x;
    int tx = tid % NTX, ty = tid / NTX;
    int n0 = blockIdx.x * BN, m0 = blockIdx.y * BM;
    int bz = blockIdx.z;
    int batch = bz / SPLITK, kz = bz - batch * SPLITK;
    int Kc = K / SPLITK;
    int k0 = kz * Kc, k1 = k0 + Kc;
    A += (long)batch * sA; B += (long)batch * sB; C += (long)batch * sC;
    const float* bp = bias ? bias + (long)batch * sBias : nullptr;
    float acc[TM][TN] = {};
    for (int kt = k0; kt < k1; kt += BK) {
        constexpr int A4 = BM * BK / 4;
        #pragma unroll
        for (int e0 = 0; e0 < A4; e0 += 256) {
            int e = e0 + tid;
            int rr = e / KG, kg = (e - rr * KG) * 4;
            int gm = m0 + rr;
            float4 v = make_float4(0.f, 0.f, 0.f, 0.f);
            if (gm < M) v = *(const float4*)(A + (long)gm * lda + kt + kg);
            As[kg + 0][rr] = v.x; As[kg + 1][rr] = v.y; As[kg + 2][rr] = v.z; As[kg + 3][rr] = v.w;
        }
        constexpr int B4 = BN * BK / 4;
        #pragma unroll
        for (int e0 = 0; e0 < B4; e0 += 256) {
            int e = e0 + tid;
            int rr = e / KG, kg = (e - rr * KG) * 4;
            int gn = n0 + rr;
            float4 v = make_float4(0.f, 0.f, 0.f, 0.f);
            if (gn < N) v = *(const float4*)(B + (long)gn * ldb + kt + kg);
            Bs[kg + 0][rr] = v.x; Bs[kg + 1][rr] = v.y; Bs[kg + 2][rr] = v.z; Bs[kg + 3][rr] = v.w;
        }
        __syncthreads();
        #pragma unroll
        for (int k = 0; k < BK; ++k) {
            float a[TM], b[TN];
            #pragma unroll
            for (int i = 0; i < TM; i += 4) *(float4*)&a[i] = *(const float4*)&As[k][ty * TM + i];
            #pragma unroll
            for (int j = 0; j < TN; j += 4) *(float4*)&b[j] = *(const float4*)&Bs[k][tx * TN + j];
            #pragma unroll
            for (int i = 0; i < TM; ++i) {
                #pragma unroll
                for (int j = 0; j < TN; ++j) acc[i][j] += a[i] * b[j];
            }
        }
        __syncthreads();
    }
    #pragma unroll
    for (int i = 0; i < TM; ++i) {
        int gm = m0 + ty * TM + i;
        if (gm < M) {
            #pragma unroll
            for (int j = 0; j < TN; ++j) {
                int gn = n0 + tx * TN + j;
                if (gn < N) {
                    float v = acc[i][j];
                    if (SPLITK > 1) {
                        atomicAdd(&C[(long)gm * ldc + gn], v);
                    } else {
                        if (bp) v += bp[gn];
                        if (ACT == 1) v = fmaxf(v, 0.0f);
                        C[(long)gm * ldc + gn] = v;
                    }
                }
            }
        }
    }
}

// ===========================================================================
// bf16 MFMA GEMM (m97 structure): C = act(A @ B^T + bias)
// SPLITK>1: blockIdx.z = kz; plain-store partials to Cf + kz*M*N (no atomics).
// ===========================================================================
template <int ACT, int OUT_MODE, int SPLITK = 1>
__global__ __launch_bounds__(256) void gemm_bf16(
    const ushort* __restrict__ A, const ushort* __restrict__ B,
    const float* __restrict__ bias, float* __restrict__ Cf,
    ushort* __restrict__ Cb, int M, int N, int K)
{
    __shared__ __align__(16) ushort As[8192];
    __shared__ __align__(16) ushort Bs[8192];
    int tid = threadIdx.x;
    int wave = tid >> 6, lane = tid & 63;
    int m0 = blockIdx.y * 128, n0 = blockIdx.x * 128;
    const ushort* ga = A + (long)(m0 + wave * 32 + (lane >> 3)) * K + (lane & 7) * 8;
    const ushort* gb = B + (long)(n0 + wave * 32 + (lane >> 3)) * K + (lane & 7) * 8;
    ushort* la = &As[wave * 2048];
    ushort* lb = &Bs[wave * 2048];
    int wr = wave >> 1, wc = wave & 1;
    int fr = lane & 15, ks = (lane >> 4) * 8;
    f32x4 acc[4][4];
    #pragma unroll
    for (int i = 0; i < 4; ++i)
        #pragma unroll
        for (int j = 0; j < 4; ++j) acc[i][j] = (f32x4){0.f, 0.f, 0.f, 0.f};

    int k0 = 0, k1 = K;
    if (SPLITK > 1) { int Kc = K / SPLITK; k0 = blockIdx.z * Kc; k1 = k0 + Kc; }
    for (int kt = k0; kt < k1; kt += 64) {
        #pragma unroll
        for (int i = 0; i < 4; ++i) {
            gload_lds16(ga + kt + (long)i * 8 * K, la + i * 512);
            gload_lds16(gb + kt + (long)i * 8 * K, lb + i * 512);
        }
        __syncthreads();
        #pragma unroll
        for (int kk = 0; kk < 64; kk += 32) {
            s16x8 af[4], bfr[4];
            #pragma unroll
            for (int m = 0; m < 4; ++m)
                af[m] = *(const s16x8*)&As[(wr * 64 + m * 16 + fr) * 64 + kk + ks];
            #pragma unroll
            for (int n = 0; n < 4; ++n)
                bfr[n] = *(const s16x8*)&Bs[(wc * 64 + n * 16 + fr) * 64 + kk + ks];
            #pragma unroll
            for (int m = 0; m < 4; ++m)
                #pragma unroll
                for (int n = 0; n < 4; ++n)
                    acc[m][n] = __builtin_amdgcn_mfma_f32_16x16x32_bf16(
                        af[m], bfr[n], acc[m][n], 0, 0, 0);
        }
        __syncthreads();
    }
    int cr = (lane >> 4) * 4;
    #pragma unroll
    for (int n = 0; n < 4; ++n) {
        int col = n0 + wc * 64 + n * 16 + fr;
        float bv = (SPLITK == 1 && bias) ? bias[col] : 0.f;
        #pragma unroll
        for (int m = 0; m < 4; ++m) {
            #pragma unroll
            for (int j = 0; j < 4; ++j) {
                int row = m0 + wr * 64 + m * 16 + cr + j;
                float v = acc[m][n][j] + bv;
                if (SPLITK > 1) {
                    Cf[(long)blockIdx.z * M * N + (long)row * N + col] = v;
                } else {
                    if (ACT == 1) v = fmaxf(v, 0.f);
                    if (OUT_MODE != 2) Cf[(long)row * N + col] = v;
                    if (OUT_MODE != 0) Cb[(long)row * N + col] = f2bf(v);
                }
            }
        }
    }
}

// ===========================================================================
// f1 partials reduce: out[i] = relu(sum_s part[s*131072+i] + bias[i%512])
// ===========================================================================
__global__ __launch_bounds__(256) void f1_reduce(
    const float* __restrict__ part, const float* __restrict__ bias,
    float* __restrict__ out)
{
    int i = blockIdx.x * 256 + threadIdx.x;   // 131072 outputs
    float s = 0.f;
    #pragma unroll 8
    for (int k = 0; k < 64; ++k) s += part[(long)k * 131072 + i];
    out[i] = fmaxf(s + bias[i & 511], 0.f);
}

// ===========================================================================
// fp32 -> bf16 conversion, 8 elem/thread
// ===========================================================================
__global__ __launch_bounds__(256) void f2b_kernel(
    const float* __restrict__ in, ushort* __restrict__ out, int n8)
{
    int i = blockIdx.x * 256 + threadIdx.x;
    if (i >= n8) return;
    long base = (long)i * 8;
    float4 v0 = *(const float4*)(in + base);
    float4 v1 = *(const float4*)(in + base + 4);
    ushort4 a, b;
    a.x = f2bf(v0.x); a.y = f2bf(v0.y); a.z = f2bf(v0.z); a.w = f2bf(v0.w);
    b.x = f2bf(v1.x); b.y = f2bf(v1.y); b.z = f2bf(v1.z); b.w = f2bf(v1.w);
    *(ushort4*)(out + base) = a;
    *(ushort4*)(out + base + 4) = b;
}

// ===========================================================================
// Grouped attention + o-proj + residual + LayerNorm(64).  Output bf16.
// ===========================================================================
__global__ __launch_bounds__(256) void gatt_ln(
    const float* __restrict__ qkv, const float* __restrict__ u,
    const float* __restrict__ wo, const float* __restrict__ bo,
    const float* __restrict__ lnw, const float* __restrict__ lnb,
    ushort* __restrict__ out)
{
    __shared__ float sm[12928];
    float* qs  = sm;
    float* ks  = sm + 2112;
    float* vs  = sm + 4160;
    float* wos = sm + 6208;
    float* os  = sm + 10560;
    float* psT = sm;
    float* bos = sm + 12736;
    float* lws = sm + 12800;
    float* lbs = sm + 12864;
    int gb = blockIdx.x;
    int g = gb >> 8, b = gb & 255;
    int tid = threadIdx.x;

    const float* base = qkv + (long)g * 1572864 + b * 192;
    for (int e = tid; e < 1536; e += 256) {
        int s = e / 48, c4 = (e - s * 48) * 4;
        float4 v = *(const float4*)(base + (long)s * 49152 + c4);
        if (c4 < 64) {
            float* q = &qs[s * 66 + c4];
            q[0] = v.x * 0.25f; q[1] = v.y * 0.25f; q[2] = v.z * 0.25f; q[3] = v.w * 0.25f;
        } else if (c4 < 128) {
            *(float4*)&ks[s * 64 + (c4 - 64)] = v;
        } else {
            *(float4*)&vs[s * 64 + (c4 - 128)] = v;
        }
    }
    const float* wog = wo + g * 4096;
    for (int i = tid; i < 4096; i += 256) wos[(i >> 6) * 68 + (i & 63)] = wog[i];
    if (tid < 64) { bos[tid] = bo[g * 64 + tid]; lws[tid] = lnw[tid]; lbs[tid] = lnb[tid]; }
    __syncthreads();

    int hr = tid >> 1;
    int h = hr >> 5, qi = hr & 31, half = tid & 1;
    float qreg[16];
    #pragma unroll
    for (int d2 = 0; d2 < 16; d2 += 2)
        *(float2*)&qreg[d2] = *(const float2*)&qs[qi * 66 + h * 16 + d2];
    float sc[16];
    #pragma unroll
    for (int jj = 0; jj < 16; ++jj) {
        int j = half * 16 + jj;
        const float* kr = &ks[j * 64 + h * 16];
        float a = 0.f;
        #pragma unroll
        for (int d4 = 0; d4 < 16; d4 += 4) {
            float4 kv = *(const float4*)&kr[d4];
            a += qreg[d4] * kv.x + qreg[d4 + 1] * kv.y + qreg[d4 + 2] * kv.z + qreg[d4 + 3] * kv.w;
        }
        sc[jj] = a;
    }
    float mx = sc[0];
    #pragma unroll
    for (int jj = 1; jj < 16; ++jj) mx = fmaxf(mx, sc[jj]);
    mx = fmaxf(mx, __shfl_xor(mx, 1));
    float sum = 0.f;
    #pragma unroll
    for (int jj = 0; jj < 16; ++jj) { sc[jj] = __expf(sc[jj] - mx); sum += sc[jj]; }
    sum += __shfl_xor(sum, 1);
    float inv = 1.0f / sum;
    __syncthreads();
    #pragma unroll
    for (int jj = 0; jj < 16; ++jj)
        psT[(half * 16 + jj) * 128 + h * 32 + qi] = sc[jj] * inv;
    __syncthreads();

    int si = tid >> 3, e0 = (tid & 7) * 8;
    int hh = e0 >> 4;
    float oacc[8] = {};
    for (int j = 0; j < 32; ++j) {
        float pj = psT[j * 128 + hh * 32 + si];
        const float* vr = &vs[j * 64 + e0];
        float4 v0 = *(const float4*)&vr[0];
        float4 v1 = *(const float4*)&vr[4];
        oacc[0] += pj * v0.x; oacc[1] += pj * v0.y; oacc[2] += pj * v0.z; oacc[3] += pj * v0.w;
        oacc[4] += pj * v1.x; oacc[5] += pj * v1.y; oacc[6] += pj * v1.z; oacc[7] += pj * v1.w;
    }
    #pragma unroll
    for (int e = 0; e < 8; ++e) os[si * 68 + e0 + e] = oacc[e];
    __syncthreads();

    int r8 = tid & 7;
    float z[8];
    {
        float accq[8];
        #pragma unroll
        for (int q = 0; q < 8; ++q) accq[q] = bos[r8 + q * 8];
        #pragma unroll 4
        for (int e4 = 0; e4 < 64; e4 += 4) {
            float4 ov = *(const float4*)&os[si * 68 + e4];
            #pragma unroll
            for (int q = 0; q < 8; ++q) {
                float4 wv = *(const float4*)&wos[(r8 + q * 8) * 68 + e4];
                accq[q] += ov.x * wv.x + ov.y * wv.y + ov.z * wv.z + ov.w * wv.w;
            }
        }
        long ubase = (((long)g * 32 + si) * 256 + b) * 64;
        #pragma unroll
        for (int q = 0; q < 8; ++q) z[q] = accq[q] + u[ubase + r8 + q * 8];
    }
    float s1 = 0.f, s2 = 0.f;
    #pragma unroll
    for (int q = 0; q < 8; ++q) { s1 += z[q]; s2 += z[q] * z[q]; }
    #pragma unroll
    for (int off = 1; off < 8; off <<= 1) { s1 += __shfl_xor(s1, off); s2 += __shfl_xor(s2, off); }
    float mu = s1 * 0.015625f;
    float var = s2 * 0.015625f - mu * mu;
    float rstd = rsqrtf(var + EPS);
    long obase = (((long)g * 32 + si) * 256 + b) * 64;
    #pragma unroll
    for (int q = 0; q < 8; ++q) {
        int e2 = r8 + q * 8;
        out[obase + e2] = f2bf((z[q] - mu) * rstd * lws[e2] + lbs[e2]);
    }
}

// ===========================================================================
// Encoder attention (L=16, h=16, hd=128). fp32 in, bf16 out.
// ===========================================================================
__global__ __launch_bounds__(256) void enc_att(
    const float* __restrict__ qkv, ushort* __restrict__ o)
{
    __shared__ float qs[16 * 132], ks[16 * 132], vs[16 * 132], ps[16 * 17];
    int bh = blockIdx.x;
    int b2 = bh >> 4, h = bh & 15;
    int tid = threadIdx.x;
    const float qscale = 0.08838834764831845f;  // 128^-0.5
    for (int e = tid; e < 512; e += 256) {
        int l = e >> 5, c4 = (e & 31) * 4;
        long rowoff = ((long)l * 256 + b2) * 6144 + h * 128 + c4;
        float4 q = *(const float4*)(qkv + rowoff);
        float4 k = *(const float4*)(qkv + rowoff + 2048);
        float4 v = *(const float4*)(qkv + rowoff + 4096);
        q.x *= qscale; q.y *= qscale; q.z *= qscale; q.w *= qscale;
        *(float4*)&qs[l * 132 + c4] = q;
        *(float4*)&ks[l * 132 + c4] = k;
        *(float4*)&vs[l * 132 + c4] = v;
    }
    __syncthreads();
    int qi = tid >> 4, j = tid & 15;
    float acc = 0.f;
    #pragma unroll
    for (int d = 0; d < 128; d += 4) {
        float4 qv = *(const float4*)&qs[qi * 132 + d];
        float4 kv = *(const float4*)&ks[j * 132 + d];
        acc += qv.x * kv.x + qv.y * kv.y + qv.z * kv.z + qv.w * kv.w;
    }
    float m = acc;
    #pragma unroll
    for (int off = 1; off < 16; off <<= 1) m = fmaxf(m, __shfl_xor(m, off));
    float p = __expf(acc - m);
    float sum = p;
    #pragma unroll
    for (int off = 1; off < 16; off <<= 1) sum += __shfl_xor(sum, off);
    ps[qi * 17 + j] = p / sum;
    __syncthreads();
    float pr[16];
    #pragma unroll
    for (int jj = 0; jj < 16; ++jj) pr[jj] = ps[qi * 17 + jj];
    long obase = ((long)qi * 256 + b2) * 2048 + h * 128;
    #pragma unroll
    for (int qd = 0; qd < 8; ++qd) {
        int d = (tid & 15) + qd * 16;
        float a = 0.f;
        #pragma unroll
        for (int jj = 0; jj < 16; ++jj) a += pr[jj] * vs[jj * 132 + d];
        o[obase + d] = f2bf(a);
    }
}

// ===========================================================================
// residual + LayerNorm over 2048.
// ===========================================================================
template <int RSD_BF, int OUT_BF>
__global__ __launch_bounds__(256) void resid_ln(
    const float* __restrict__ y, const void* __restrict__ rsdv,
    const float* __restrict__ w, const float* __restrict__ bb,
    float* __restrict__ out, ushort* __restrict__ outb)
{
    __shared__ float red[8];
    int tid = threadIdx.x;
    long row = blockIdx.x;
    const float* yr = y + row * 2048;
    float4 a0 = *(const float4*)(yr + tid * 4);
    float4 a1 = *(const float4*)(yr + 1024 + tid * 4);
    float r[8];
    if (RSD_BF) {
        const ushort* rr = (const ushort*)rsdv + row * 2048;
        ushort4 u0 = *(const ushort4*)(rr + tid * 4);
        ushort4 u1 = *(const ushort4*)(rr + 1024 + tid * 4);
        r[0] = bf2f(u0.x); r[1] = bf2f(u0.y); r[2] = bf2f(u0.z); r[3] = bf2f(u0.w);
        r[4] = bf2f(u1.x); r[5] = bf2f(u1.y); r[6] = bf2f(u1.z); r[7] = bf2f(u1.w);
    } else {
        const float* rr = (const float*)rsdv + row * 2048;
        float4 r0 = *(const float4*)(rr + tid * 4);
        float4 r1 = *(const float4*)(rr + 1024 + tid * 4);
        r[0] = r0.x; r[1] = r0.y; r[2] = r0.z; r[3] = r0.w;
        r[4] = r1.x; r[5] = r1.y; r[6] = r1.z; r[7] = r1.w;
    }
    float v[8] = { a0.x + r[0], a0.y + r[1], a0.z + r[2], a0.w + r[3],
                   a1.x + r[4], a1.y + r[5], a1.z + r[6], a1.w + r[7] };
    float s1 = 0.f, s2 = 0.f;
    #pragma unroll
    for (int i = 0; i < 8; ++i) { s1 += v[i]; s2 += v[i] * v[i]; }
    #pragma unroll
    for (int off = 1; off < 64; off <<= 1) { s1 += __shfl_xor(s1, off); s2 += __shfl_xor(s2, off); }
    int wid = tid >> 6, lane = tid & 63;
    if (lane == 0) { red[wid * 2] = s1; red[wid * 2 + 1] = s2; }
    __syncthreads();
    s1 = red[0] + red[2] + red[4] + red[6];
    s2 = red[1] + red[3] + red[5] + red[7];
    float mu = s1 * (1.0f / 2048.0f);
    float var = s2 * (1.0f / 2048.0f) - mu * mu;
    float rstd = rsqrtf(var + EPS);
    float4 w0 = *(const float4*)(w + tid * 4);
    float4 w1 = *(const float4*)(w + 1024 + tid * 4);
    float4 b0 = *(const float4*)(bb + tid * 4);
    float4 b1 = *(const float4*)(bb + 1024 + tid * 4);
    float o0[8];
    o0[0] = (v[0] - mu) * rstd * w0.x + b0.x; o0[1] = (v[1] - mu) * rstd * w0.y + b0.y;
    o0[2] = (v[2] - mu) * rstd * w0.z + b0.z; o0[3] = (v[3] - mu) * rstd * w0.w + b0.w;
    o0[4] = (v[4] - mu) * rstd * w1.x + b1.x; o0[5] = (v[5] - mu) * rstd * w1.y + b1.y;
    o0[6] = (v[6] - mu) * rstd * w1.z + b1.z; o0[7] = (v[7] - mu) * rstd * w1.w + b1.w;
    *(float4*)(out + row * 2048 + tid * 4) = *(float4*)&o0[0];
    *(float4*)(out + row * 2048 + 1024 + tid * 4) = *(float4*)&o0[4];
    if (OUT_BF) {
        ushort4 q0, q1;
        q0.x = f2bf(o0[0]); q0.y = f2bf(o0[1]); q0.z = f2bf(o0[2]); q0.w = f2bf(o0[3]);
        q1.x = f2bf(o0[4]); q1.y = f2bf(o0[5]); q1.z = f2bf(o0[6]); q1.w = f2bf(o0[7]);
        *(ushort4*)(outb + row * 2048 + tid * 4) = q0;
        *(ushort4*)(outb + row * 2048 + 1024 + tid * 4) = q1;
    }
}

// ===========================================================================
extern "C" void kernel_launch(void* const* d_in, const int* in_sizes, int n_in,
                              void* d_out, int out_size, void* d_ws, size_t ws_size,
                              hipStream_t stream)
{
    (void)in_sizes; (void)n_in; (void)out_size; (void)ws_size;
    const float* t        = (const float*)d_in[0];
    const float* conv1_w  = (const float*)d_in[1];
    const float* conv1_b  = (const float*)d_in[2];
    const float* conv2_w  = (const float*)d_in[3];
    const float* conv2_b  = (const float*)d_in[4];
    const float* expand_w = (const float*)d_in[5];
    const float* expand_b = (const float*)d_in[6];
    const float* mha_wqkv = (const float*)d_in[7];
    const float* mha_bqkv = (const float*)d_in[8];
    const float* mha_wo   = (const float*)d_in[9];
    const float* mha_bo   = (const float*)d_in[10];
    const float* ln1_w    = (const float*)d_in[11];
    const float* ln1_b    = (const float*)d_in[12];
    const float* enc_wqkv = (const float*)d_in[13];
    const float* enc_bqkv = (const float*)d_in[14];
    const float* enc_wo   = (const float*)d_in[15];
    const float* enc_bo   = (const float*)d_in[16];
    const float* enc_ln1w = (const float*)d_in[17];
    const float* enc_ln1b = (const float*)d_in[18];
    const float* enc_w1   = (const float*)d_in[19];
    const float* enc_b1   = (const float*)d_in[20];
    const float* enc_w2   = (const float*)d_in[21];
    const float* enc_b2   = (const float*)d_in[22];
    const float* enc_ln2w = (const float*)d_in[23];
    const float* enc_ln2b = (const float*)d_in[24];
    const float* f1_w     = (const float*)d_in[25];
    const float* f1_b     = (const float*)d_in[26];
    const float* f2_w     = (const float*)d_in[27];
    const float* f2_b     = (const float*)d_in[28];
    const float* f3_w     = (const float*)d_in[29];
    const float* f3_b     = (const float*)d_in[30];
    float* out = (float*)d_out;

    float* W = (float*)d_ws;
    // ---- region plan (float offsets), lifetimes verified: ----
    ushort* u1b    = (ushort*)W;               // [0,14745600)            c1->c2 (bf16 now)
    float*  u2     = W + 29491200;             // [29491200,34209792)     c2->ex
    float*  u      = W + 34209792;             // [34209792,42598400)     ex->gatt
    float*  qkvg   = W;                        // [0,25165824)            gq->gatt (u1 dead)
    ushort* uln_b  = (ushort*)(W + 42598400);  // [42598400,46792704)     gatt->ln1
    ushort* wk     = (ushort*)(W + 46800000);  // [46800000,46804608)     prep->conv2
    ushort* wqkv_b = (ushort*)(W);             // [0,6291456)             conv->qkvgemm (qkvg dead)
    ushort* wo_b   = (ushort*)(W + 6291456);   // [6291456,8388608)       conv->oproj
    ushort* w1_b   = (ushort*)(W + 33554432);  // [33554432,35651584)     conv->ffn1 (u2/u dead)
    ushort* w2_b   = (ushort*)(W + 35651584);  // [35651584,37748736)     conv->ffn2
    float*  qkv2   = W + 8388608;              // [8388608,33554432)      qkvgemm->encatt
    ushort* obuf_b = (ushort*)(W + 37748736);  // [37748736,41943040)     encatt->oproj
    float*  ytmp   = W + 8388608;              // [8388608,16777216)      oproj->ln1, ffn2->ln2 (qkv2 dead)
    float*  x1     = W + 16777216;             // [16777216,25165824)     ln1->ln2
    ushort* x1_b   = (ushort*)(W + 25165824);  // [25165824,29360128)     ln1->ffn1
    ushort* hbuf_b = (ushort*)(W + 29360128);  // [29360128,33554432)     ffn1->ffn2
    float*  x2     = W;                        // [0,8388608)             ln2 out (weights_b dead)
    ushort* x2_b   = (ushort*)(W + 37748736);  // [37748736,39845888)     ln2->f1 (obuf dead)
    ushort* f1w_b  = (ushort*)(W + 25165824);  // [25165824,33554432)     ln2->f1 (x1_b/hbuf dead)
    float*  f1part = W + 8388608;              // [8388608,16777216)      f1->reduce (ytmp dead)
    float*  f1o    = W + 16777216;             // [16777216,16908288)     reduce->f2 (x1 dead)
    float*  f2o    = W + 16908288;             // [16908288,16941056)

    dim3 blk(256);
    convw_prep<<<36, blk, 0, stream>>>(conv2_w, wk);
    conv1_pool<<<4096, blk, 0, stream>>>(t, conv1_w, conv1_b, u1b);
    conv2_mfma<<<2048, blk, 0, stream>>>(u1b, wk, conv2_b, u2);
    expand_k<<<2048, blk, 0, stream>>>(u2, expand_w, expand_b, u);
    // grouped qkv (fp32): per g (8192,64)@(64,192)^T
    gemm_tn<64, 64, 16, 4, 4, 0, 1><<<dim3(3, 128, 16), blk, 0, stream>>>(
        u, mha_wqkv, mha_bqkv, qkvg, 8192, 192, 64, 64, 64, 192,
        524288L, 12288L, 192L, 1572864L);
    gatt_ln<<<4096, blk, 0, stream>>>(qkvg, u, mha_wo, mha_bo, ln1_w, ln1_b, uln_b);
    // weight conversions (regions qkvg/u dead now)
    f2b_kernel<<<6144, blk, 0, stream>>>(enc_wqkv, wqkv_b, 1572864);
    f2b_kernel<<<2048, blk, 0, stream>>>(enc_wo, wo_b, 524288);
    f2b_kernel<<<2048, blk, 0, stream>>>(enc_w1, w1_b, 524288);
    f2b_kernel<<<2048, blk, 0, stream>>>(enc_w2, w2_b, 524288);
    // encoder qkv (bf16 MFMA): (4096,2048)@(2048,6144)^T -> fp32
    gemm_bf16<0, 0><<<dim3(48, 32), blk, 0, stream>>>(
        uln_b, wqkv_b, enc_bqkv, qkv2, nullptr, 4096, 6144, 2048);
    enc_att<<<4096, blk, 0, stream>>>(qkv2, obuf_b);
    // o-proj (bf16 MFMA) -> fp32
    gemm_bf16<0, 0><<<dim3(16, 32), blk, 0, stream>>>(
        obuf_b, wo_b, enc_bo, ytmp, nullptr, 4096, 2048, 2048);
    resid_ln<1, 1><<<4096, blk, 0, stream>>>(ytmp, uln_b, enc_ln1w, enc_ln1b, x1, x1_b);
    // FFN1 (bf16 MFMA, relu, bf16-only out)
    gemm_bf16<1, 2><<<dim3(16, 32), blk, 0, stream>>>(
        x1_b, w1_b, enc_b1, nullptr, hbuf_b, 4096, 2048, 2048);
    // FFN2 (bf16 MFMA) -> fp32
    gemm_bf16<0, 0><<<dim3(16, 32), blk, 0, stream>>>(
        hbuf_b, w2_b, enc_b2, ytmp, nullptr, 4096, 2048, 2048);
    // ln2: fp32 out x2 (unused downstream but cheap) + bf16 x2_b for f1
    resid_ln<0, 1><<<4096, blk, 0, stream>>>(ytmp, x1, enc_ln2w, enc_ln2b, x2, x2_b);
    // f1 (bf16 MFMA, split-K=64, partials + reduce; no atomics):
    f2b_kernel<<<8192, blk, 0, stream>>>(f1_w, f1w_b, 2097152);
    gemm_bf16<0, 0, 64><<<dim3(4, 2, 64), blk, 0, stream>>>(
        x2_b, f1w_b, nullptr, f1part, nullptr, 256, 512, 32768);
    f1_reduce<<<512, blk, 0, stream>>>(f1part, f1_b, f1o);
    // f2: (256,512)@(512,128)^T + relu (fp32)
    gemm_tn<64, 64, 16, 4, 4, 1, 1><<<dim3(2, 4, 1), blk, 0, stream>>>(
        f1o, f2_w, f2_b, f2o, 256, 128, 512, 512, 512, 128, 0, 0, 0, 0);
    // f3: (256,128)@(128,25)^T -> d_out (fp32)
    gemm_tn<64, 64, 16, 4, 4, 0, 1><<<dim3(1, 4, 1), blk, 0, stream>>>(
        f2o, f3_w, f3_b, out, 256, 25, 128, 128, 128, 25, 0, 0, 0, 0);
}

// Round 9
// 944.497 us; speedup vs baseline: 3.9894x; 1.0636x over previous
//
#include <hip/hip_runtime.h>

// ---------------------------------------------------------------------------
// Round 9: kill the last fp32 GEMM + fp32 intermediate traffic.
// (a) grouped qkv: fp32 gemm_tn (est ~100us, BK=16 overhead-bound, 100MB fp32
//     write) -> batched bf16 MFMA gqkv_mfma, bf16 output (50MB); gatt_ln
//     staging reads bf16.
// (b) encoder qkv output bf16 (96->48MB write); enc_att staging reads bf16.
// (c) ln2 drops its dead fp32 output.
// Everything else identical to passing round-8 kernel (1005us, absmax 2e-3).
// ---------------------------------------------------------------------------

#define EPS 1e-5f

typedef __attribute__((ext_vector_type(8))) short s16x8;
typedef __attribute__((ext_vector_type(4))) float f32x4;

__device__ inline float bf2f(ushort u) {
    union { unsigned u; float f; } x; x.u = ((unsigned)u) << 16; return x.f;
}
__device__ inline ushort f2bf(float f) {
    union { float f; unsigned u; } x; x.f = f;
    unsigned r = x.u + 0x7FFFu + ((x.u >> 16) & 1u);   // RTNE
    return (ushort)(r >> 16);
}
__device__ inline void gload_lds16(const void* g, void* l) {
    __builtin_amdgcn_global_load_lds(
        (const __attribute__((address_space(1))) unsigned int*)g,
        (__attribute__((address_space(3))) unsigned int*)l, 16, 0, 0);
}

// ===========================================================================
// conv1 (1->32, 3x3 VALID) + maxpool2 on a 32x32 tile. Output bf16.
// ===========================================================================
__global__ __launch_bounds__(256) void conv1_pool(
    const float* __restrict__ t, const float* __restrict__ w,
    const float* __restrict__ bias, ushort* __restrict__ out)
{
    __shared__ float tile[32][33];
    __shared__ float ws9[288];
    __shared__ float bs[32];
    int n = blockIdx.x, tid = threadIdx.x;
    int b = n >> 4, tt = n & 15, ty = tt >> 2, tx = tt & 3;
    const float* tb = t + (long)b * 16384 + ty * 32 * 128 + tx * 32;
    for (int i = tid; i < 1024; i += 256) {
        int r = i >> 5, cc = i & 31;
        tile[r][cc] = tb[r * 128 + cc] * (1.0f / 255.0f);
    }
    for (int i = tid; i < 288; i += 256) ws9[i] = w[i];
    if (tid < 32) bs[tid] = bias[tid];
    __syncthreads();
    for (int o = tid; o < 7200; o += 256) {
        int c = o / 225, p = o - c * 225;
        int py = p / 15, px = p - py * 15;
        float in[4][4];
        #pragma unroll
        for (int iy = 0; iy < 4; ++iy) {
            #pragma unroll
            for (int ix = 0; ix < 4; ++ix) in[iy][ix] = tile[py * 2 + iy][px * 2 + ix];
        }
        float b0 = bs[c];
        float a00 = b0, a01 = b0, a10 = b0, a11 = b0;
        const float* wc = &ws9[c * 9];
        #pragma unroll
        for (int ky = 0; ky < 3; ++ky) {
            #pragma unroll
            for (int kx = 0; kx < 3; ++kx) {
                float wv = wc[ky * 3 + kx];
                a00 += in[ky][kx] * wv;     a01 += in[ky][kx + 1] * wv;
                a10 += in[ky + 1][kx] * wv; a11 += in[ky + 1][kx + 1] * wv;
            }
        }
        out[(long)n * 7200 + o] = f2bf(fmaxf(fmaxf(a00, a01), fmaxf(a10, a11)));
    }
}

// ===========================================================================
// weight prep for conv2 MFMA: w (32oc,32ci,3,3) fp32 -> wk (9kz,32oc,32ci) bf16
// ===========================================================================
__global__ __launch_bounds__(256) void convw_prep(
    const float* __restrict__ w, ushort* __restrict__ wk)
{
    int i = blockIdx.x * 256 + threadIdx.x;   // 9216 elems
    if (i >= 9216) return;
    int kz = i >> 10, rem = i & 1023;          // rem = oc*32+ci
    int oc = rem >> 5, ci = rem & 31;
    wk[i] = f2bf(w[oc * 288 + ci * 9 + kz]);
}

// ===========================================================================
// conv2 (32->32, 3x3 VALID on 15x15) + maxpool2 -> (4096, 32, 6, 6)
// bf16 MFMA implicit GEMM. u1 input bf16.
// ===========================================================================
__global__ __launch_bounds__(256) void conv2_mfma(
    const ushort* __restrict__ u1, const ushort* __restrict__ wk,
    const float* __restrict__ bias, float* __restrict__ u2)
{
    __shared__ __align__(16) ushort tiles[2][7680];   // 2 x 15,360 B (240 rows x 64 B)
    __shared__ float hp[2][2376];                     // 2 x 72 rows x 33 (pad) f32
    int tid = threadIdx.x;
    int wave = tid >> 6, lane = tid & 63;
    int n0 = blockIdx.x * 2;

    for (int u = tid; u < 1800; u += 256) {
        int img = u / 900, v = u - img * 900;
        int ks = v / 225, pos = v - ks * 225;      // ks: ci-chunk of 8
        int y = pos / 15, x = pos - y * 15;
        const ushort* src = u1 + (long)(n0 + img) * 7200 + (ks * 8) * 225 + pos;
        union { s16x8 v8; ushort us[8]; } pk;
        #pragma unroll
        for (int j = 0; j < 8; ++j) pk.us[j] = src[j * 225];
        int r = y * 16 + x;
        int chunk = ks ^ ((r >> 1) & 3);
        *(s16x8*)((char*)&tiles[img][0] + r * 64 + (chunk << 4)) = pk.v8;
    }
    __syncthreads();

    int img = wave >> 1, nf = wave & 1;
    int fr = lane & 15, ks4 = lane >> 4;
    int rb[9];
    #pragma unroll
    for (int m = 0; m < 9; ++m) {
        int pos = m * 16 + fr;
        int py = pos / 12, px = pos - py * 12;
        rb[m] = py * 16 + px;
    }
    f32x4 acc[9];
    #pragma unroll
    for (int m = 0; m < 9; ++m) acc[m] = (f32x4){0.f, 0.f, 0.f, 0.f};
    const char* tbase = (const char*)&tiles[img][0];
    #pragma unroll
    for (int kz = 0; kz < 9; ++kz) {
        int ky = kz / 3, kx = kz - ky * 3;
        s16x8 bf = *(const s16x8*)(wk + kz * 1024 + (nf * 16 + fr) * 32 + ks4 * 8);
        #pragma unroll
        for (int m = 0; m < 9; ++m) {
            int r = rb[m] + ky * 16 + kx;
            s16x8 af = *(const s16x8*)(tbase + r * 64 + ((ks4 ^ ((r >> 1) & 3)) << 4));
            acc[m] = __builtin_amdgcn_mfma_f32_16x16x32_bf16(af, bf, acc[m], 0, 0, 0);
        }
    }

    int oc = nf * 16 + fr;
    int cr4 = ks4 * 4;
    #pragma unroll
    for (int m = 0; m < 9; ++m) {
        float v01 = fmaxf(acc[m][0], acc[m][1]);
        float v23 = fmaxf(acc[m][2], acc[m][3]);
        int p0 = m * 16 + cr4;
        int py = p0 / 12, px0 = p0 - py * 12;
        int rowb = py * 6 + (px0 >> 1);
        hp[img][rowb * 33 + oc] = v01;
        hp[img][(rowb + 1) * 33 + oc] = v23;
    }
    __syncthreads();

    for (int u = tid; u < 2304; u += 256) {
        int im = u / 1152, v = u - im * 1152;
        int o = v / 36, opos = v - o * 36;
        int i = opos / 6, jj = opos - i * 6;
        float a = hp[im][((2 * i) * 6 + jj) * 33 + o];
        float b = hp[im][((2 * i + 1) * 6 + jj) * 33 + o];
        u2[(long)(n0 + im) * 1152 + o * 36 + opos] = fmaxf(a, b) + bias[o];
    }
}

// ===========================================================================
// expand: relu( (131072, 36) @ (36, 64)^T + b ).  Dual out: fp32 u + bf16 u_b.
// ===========================================================================
__global__ __launch_bounds__(256) void expand_k(
    const float* __restrict__ u2, const float* __restrict__ w,
    const float* __restrict__ bias, float* __restrict__ out,
    ushort* __restrict__ outb)
{
    __shared__ float ws[2304];
    __shared__ float xs[2304];
    __shared__ float bs[64];
    int tid = threadIdx.x;
    long r0 = (long)blockIdx.x * 64;
    const float* src = u2 + r0 * 36;
    for (int i = tid; i < 2304; i += 256) { ws[i] = w[i]; xs[i] = src[i]; }
    if (tid < 64) bs[tid] = bias[tid];
    __syncthreads();
    int row = tid >> 2, qq = tid & 3;
    float x[36];
    #pragma unroll
    for (int k4 = 0; k4 < 36; k4 += 4) *(float4*)&x[k4] = *(const float4*)&xs[row * 36 + k4];
    float res[16];
    #pragma unroll
    for (int eo = 0; eo < 16; ++eo) {
        int e = qq * 16 + eo;
        const float* wr = &ws[e * 36];
        float acc = bs[e];
        #pragma unroll
        for (int k4 = 0; k4 < 36; k4 += 4) {
            float4 wv = *(const float4*)&wr[k4];
            acc += x[k4] * wv.x + x[k4 + 1] * wv.y + x[k4 + 2] * wv.z + x[k4 + 3] * wv.w;
        }
        res[eo] = fmaxf(acc, 0.0f);
    }
    float* orow = out + (r0 + row) * 64 + qq * 16;
    ushort* brow = outb + (r0 + row) * 64 + qq * 16;
    #pragma unroll
    for (int v4 = 0; v4 < 4; ++v4) {
        *(float4*)(orow + v4 * 4) = *(float4*)&res[v4 * 4];
        ushort4 q;
        q.x = f2bf(res[v4 * 4 + 0]); q.y = f2bf(res[v4 * 4 + 1]);
        q.z = f2bf(res[v4 * 4 + 2]); q.w = f2bf(res[v4 * 4 + 3]);
        *(ushort4*)(brow + v4 * 4) = q;
    }
}

// ===========================================================================
// Generic fp32 GEMM (kept for f2 / f3)
// ===========================================================================
template <int BM, int BN, int BK, int TM, int TN, int ACT, int SPLITK>
__global__ __launch_bounds__(256) void gemm_tn(
    const float* __restrict__ A, const float* __restrict__ B,
    const float* __restrict__ bias, float* __restrict__ C,
    int M, int N, int K, int lda, int ldb, int ldc,
    long sA, long sB, long sBias, long sC)
{
    constexpr int NTX = BN / TN;
    constexpr int KG = BK / 4;
    __shared__ float As[BK][BM + 4];
    __shared__ float Bs[BK][BN + 4];
    int tid = threadIdx.x;
    int tx = tid % NTX, ty = tid / NTX;
    int n0 = blockIdx.x * BN, m0 = blockIdx.y * BM;
    int bz = blockIdx.z;
    int batch = bz / SPLITK, kz = bz - batch * SPLITK;
    int Kc = K / SPLITK;
    int k0 = kz * Kc, k1 = k0 + Kc;
    A += (long)batch * sA; B += (long)batch * sB; C += (long)batch * sC;
    const float* bp = bias ? bias + (long)batch * sBias : nullptr;
    float acc[TM][TN] = {};
    for (int kt = k0; kt < k1; kt += BK) {
        constexpr int A4 = BM * BK / 4;
        #pragma unroll
        for (int e0 = 0; e0 < A4; e0 += 256) {
            int e = e0 + tid;
            int rr = e / KG, kg = (e - rr * KG) * 4;
            int gm = m0 + rr;
            float4 v = make_float4(0.f, 0.f, 0.f, 0.f);
            if (gm < M) v = *(const float4*)(A + (long)gm * lda + kt + kg);
            As[kg + 0][rr] = v.x; As[kg + 1][rr] = v.y; As[kg + 2][rr] = v.z; As[kg + 3][rr] = v.w;
        }
        constexpr int B4 = BN * BK / 4;
        #pragma unroll
        for (int e0 = 0; e0 < B4; e0 += 256) {
            int e = e0 + tid;
            int rr = e / KG, kg = (e - rr * KG) * 4;
            int gn = n0 + rr;
            float4 v = make_float4(0.f, 0.f, 0.f, 0.f);
            if (gn < N) v = *(const float4*)(B + (long)gn * ldb + kt + kg);
            Bs[kg + 0][rr] = v.x; Bs[kg + 1][rr] = v.y; Bs[kg + 2][rr] = v.z; Bs[kg + 3][rr] = v.w;
        }
        __syncthreads();
        #pragma unroll
        for (int k = 0; k < BK; ++k) {
            float a[TM], b[TN];
            #pragma unroll
            for (int i = 0; i < TM; i += 4) *(float4*)&a[i] = *(const float4*)&As[k][ty * TM + i];
            #pragma unroll
            for (int j = 0; j < TN; j += 4) *(float4*)&b[j] = *(const float4*)&Bs[k][tx * TN + j];
            #pragma unroll
            for (int i = 0; i < TM; ++i) {
                #pragma unroll
                for (int j = 0; j < TN; ++j) acc[i][j] += a[i] * b[j];
            }
        }
        __syncthreads();
    }
    #pragma unroll
    for (int i = 0; i < TM; ++i) {
        int gm = m0 + ty * TM + i;
        if (gm < M) {
            #pragma unroll
            for (int j = 0; j < TN; ++j) {
                int gn = n0 + tx * TN + j;
                if (gn < N) {
                    float v = acc[i][j];
                    if (SPLITK > 1) {
                        atomicAdd(&C[(long)gm * ldc + gn], v);
                    } else {
                        if (bp) v += bp[gn];
                        if (ACT == 1) v = fmaxf(v, 0.0f);
                        C[(long)gm * ldc + gn] = v;
                    }
                }
            }
        }
    }
}

// ===========================================================================
// bf16 MFMA GEMM (m97 structure): C = act(A @ B^T + bias)
// OUT_MODE: 0 = fp32, 2 = bf16.  SPLITK>1: plain-store fp32 partials.
// ===========================================================================
template <int ACT, int OUT_MODE, int SPLITK = 1>
__global__ __launch_bounds__(256) void gemm_bf16(
    const ushort* __restrict__ A, const ushort* __restrict__ B,
    const float* __restrict__ bias, float* __restrict__ Cf,
    ushort* __restrict__ Cb, int M, int N, int K)
{
    __shared__ __align__(16) ushort As[8192];
    __shared__ __align__(16) ushort Bs[8192];
    int tid = threadIdx.x;
    int wave = tid >> 6, lane = tid & 63;
    int m0 = blockIdx.y * 128, n0 = blockIdx.x * 128;
    const ushort* ga = A + (long)(m0 + wave * 32 + (lane >> 3)) * K + (lane & 7) * 8;
    const ushort* gb = B + (long)(n0 + wave * 32 + (lane >> 3)) * K + (lane & 7) * 8;
    ushort* la = &As[wave * 2048];
    ushort* lb = &Bs[wave * 2048];
    int wr = wave >> 1, wc = wave & 1;
    int fr = lane & 15, ks = (lane >> 4) * 8;
    f32x4 acc[4][4];
    #pragma unroll
    for (int i = 0; i < 4; ++i)
        #pragma unroll
        for (int j = 0; j < 4; ++j) acc[i][j] = (f32x4){0.f, 0.f, 0.f, 0.f};

    int k0 = 0, k1 = K;
    if (SPLITK > 1) { int Kc = K / SPLITK; k0 = blockIdx.z * Kc; k1 = k0 + Kc; }
    for (int kt = k0; kt < k1; kt += 64) {
        #pragma unroll
        for (int i = 0; i < 4; ++i) {
            gload_lds16(ga + kt + (long)i * 8 * K, la + i * 512);
            gload_lds16(gb + kt + (long)i * 8 * K, lb + i * 512);
        }
        __syncthreads();
        #pragma unroll
        for (int kk = 0; kk < 64; kk += 32) {
            s16x8 af[4], bfr[4];
            #pragma unroll
            for (int m = 0; m < 4; ++m)
                af[m] = *(const s16x8*)&As[(wr * 64 + m * 16 + fr) * 64 + kk + ks];
            #pragma unroll
            for (int n = 0; n < 4; ++n)
                bfr[n] = *(const s16x8*)&Bs[(wc * 64 + n * 16 + fr) * 64 + kk + ks];
            #pragma unroll
            for (int m = 0; m < 4; ++m)
                #pragma unroll
                for (int n = 0; n < 4; ++n)
                    acc[m][n] = __builtin_amdgcn_mfma_f32_16x16x32_bf16(
                        af[m], bfr[n], acc[m][n], 0, 0, 0);
        }
        __syncthreads();
    }
    int cr = (lane >> 4) * 4;
    #pragma unroll
    for (int n = 0; n < 4; ++n) {
        int col = n0 + wc * 64 + n * 16 + fr;
        float bv = (SPLITK == 1 && bias) ? bias[col] : 0.f;
        #pragma unroll
        for (int m = 0; m < 4; ++m) {
            #pragma unroll
            for (int j = 0; j < 4; ++j) {
                int row = m0 + wr * 64 + m * 16 + cr + j;
                float v = acc[m][n][j] + bv;
                if (SPLITK > 1) {
                    Cf[(long)blockIdx.z * M * N + (long)row * N + col] = v;
                } else {
                    if (ACT == 1) v = fmaxf(v, 0.f);
                    if (OUT_MODE != 2) Cf[(long)row * N + col] = v;
                    if (OUT_MODE != 0) Cb[(long)row * N + col] = f2bf(v);
                }
            }
        }
    }
}

// ===========================================================================
// Grouped qkv bf16 MFMA: per g, C[8192][192] = A[8192][64] @ B[192][64]^T + b
// Block = (mtile of 128, g). 4 waves x (64x96). K=64 = single stage, 2 ksteps.
// Output bf16 at qkvg_b[g*1572864 + row*192 + col].
// ===========================================================================
__global__ __launch_bounds__(256) void gqkv_mfma(
    const ushort* __restrict__ A, const ushort* __restrict__ B,
    const float* __restrict__ bias, ushort* __restrict__ C)
{
    __shared__ __align__(16) ushort As[8192];    // 128 x 64
    __shared__ __align__(16) ushort Bs[12288];   // 192 x 64
    int tid = threadIdx.x;
    int wave = tid >> 6, lane = tid & 63;
    int mt = blockIdx.x, g = blockIdx.y;
    long arow0 = (long)g * 8192 + mt * 128;
    const ushort* ga = A + (arow0 + wave * 32 + (lane >> 3)) * 64 + (lane & 7) * 8;
    const ushort* gb = B + (long)g * 12288 + (wave * 48 + (lane >> 3)) * 64 + (lane & 7) * 8;
    ushort* la = &As[wave * 2048];
    ushort* lb = &Bs[wave * 3072];
    #pragma unroll
    for (int i = 0; i < 4; ++i) gload_lds16(ga + (long)i * 8 * 64, la + i * 512);
    #pragma unroll
    for (int i = 0; i < 6; ++i) gload_lds16(gb + (long)i * 8 * 64, lb + i * 512);
    __syncthreads();

    int wr = wave >> 1, wc = wave & 1;          // 2x2 waves of 64x96
    int fr = lane & 15, ks = (lane >> 4) * 8;
    f32x4 acc[4][6];
    #pragma unroll
    for (int m = 0; m < 4; ++m)
        #pragma unroll
        for (int n = 0; n < 6; ++n) acc[m][n] = (f32x4){0.f, 0.f, 0.f, 0.f};
    #pragma unroll
    for (int kk = 0; kk < 64; kk += 32) {
        s16x8 af[4], bfr[6];
        #pragma unroll
        for (int m = 0; m < 4; ++m)
            af[m] = *(const s16x8*)&As[(wr * 64 + m * 16 + fr) * 64 + kk + ks];
        #pragma unroll
        for (int n = 0; n < 6; ++n)
            bfr[n] = *(const s16x8*)&Bs[(wc * 96 + n * 16 + fr) * 64 + kk + ks];
        #pragma unroll
        for (int m = 0; m < 4; ++m)
            #pragma unroll
            for (int n = 0; n < 6; ++n)
                acc[m][n] = __builtin_amdgcn_mfma_f32_16x16x32_bf16(
                    af[m], bfr[n], acc[m][n], 0, 0, 0);
    }
    int cr = (lane >> 4) * 4;
    ushort* Cg = C + (long)g * 1572864;
    #pragma unroll
    for (int n = 0; n < 6; ++n) {
        int col = wc * 96 + n * 16 + fr;
        float bv = bias[g * 192 + col];
        #pragma unroll
        for (int m = 0; m < 4; ++m) {
            #pragma unroll
            for (int j = 0; j < 4; ++j) {
                long row = mt * 128 + wr * 64 + m * 16 + cr + j;
                Cg[row * 192 + col] = f2bf(acc[m][n][j] + bv);
            }
        }
    }
}

// ===========================================================================
// f1 partials reduce: out[i] = relu(sum_s part[s*131072+i] + bias[i%512])
// ===========================================================================
__global__ __launch_bounds__(256) void f1_reduce(
    const float* __restrict__ part, const float* __restrict__ bias,
    float* __restrict__ out)
{
    int i = blockIdx.x * 256 + threadIdx.x;
    float s = 0.f;
    #pragma unroll 8
    for (int k = 0; k < 64; ++k) s += part[(long)k * 131072 + i];
    out[i] = fmaxf(s + bias[i & 511], 0.f);
}

// ===========================================================================
// fp32 -> bf16 conversion, 8 elem/thread
// ===========================================================================
__global__ __launch_bounds__(256) void f2b_kernel(
    const float* __restrict__ in, ushort* __restrict__ out, int n8)
{
    int i = blockIdx.x * 256 + threadIdx.x;
    if (i >= n8) return;
    long base = (long)i * 8;
    float4 v0 = *(const float4*)(in + base);
    float4 v1 = *(const float4*)(in + base + 4);
    ushort4 a, b;
    a.x = f2bf(v0.x); a.y = f2bf(v0.y); a.z = f2bf(v0.z); a.w = f2bf(v0.w);
    b.x = f2bf(v1.x); b.y = f2bf(v1.y); b.z = f2bf(v1.z); b.w = f2bf(v1.w);
    *(ushort4*)(out + base) = a;
    *(ushort4*)(out + base + 4) = b;
}

// ===========================================================================
// Grouped attention + o-proj + residual + LayerNorm(64). bf16 qkv in, bf16 out.
// ===========================================================================
__global__ __launch_bounds__(256) void gatt_ln(
    const ushort* __restrict__ qkv, const float* __restrict__ u,
    const float* __restrict__ wo, const float* __restrict__ bo,
    const float* __restrict__ lnw, const float* __restrict__ lnb,
    ushort* __restrict__ out)
{
    __shared__ float sm[12928];
    float* qs  = sm;
    float* ks  = sm + 2112;
    float* vs  = sm + 4160;
    float* wos = sm + 6208;
    float* os  = sm + 10560;
    float* psT = sm;
    float* bos = sm + 12736;
    float* lws = sm + 12800;
    float* lbs = sm + 12864;
    int gb = blockIdx.x;
    int g = gb >> 8, b = gb & 255;
    int tid = threadIdx.x;

    const ushort* base = qkv + (long)g * 1572864 + b * 192;
    for (int e = tid; e < 768; e += 256) {
        int s = e / 24, c8 = (e % 24) * 8;
        union { s16x8 v8; ushort us[8]; } pk;
        pk.v8 = *(const s16x8*)(base + (long)s * 49152 + c8);
        if (c8 < 64) {
            float* q = &qs[s * 66 + c8];
            #pragma unroll
            for (int j = 0; j < 8; ++j) q[j] = bf2f(pk.us[j]) * 0.25f;
        } else if (c8 < 128) {
            float* k = &ks[s * 64 + (c8 - 64)];
            #pragma unroll
            for (int j = 0; j < 8; ++j) k[j] = bf2f(pk.us[j]);
        } else {
            float* v = &vs[s * 64 + (c8 - 128)];
            #pragma unroll
            for (int j = 0; j < 8; ++j) v[j] = bf2f(pk.us[j]);
        }
    }
    const float* wog = wo + g * 4096;
    for (int i = tid; i < 4096; i += 256) wos[(i >> 6) * 68 + (i & 63)] = wog[i];
    if (tid < 64) { bos[tid] = bo[g * 64 + tid]; lws[tid] = lnw[tid]; lbs[tid] = lnb[tid]; }
    __syncthreads();

    int hr = tid >> 1;
    int h = hr >> 5, qi = hr & 31, half = tid & 1;
    float qreg[16];
    #pragma unroll
    for (int d2 = 0; d2 < 16; d2 += 2)
        *(float2*)&qreg[d2] = *(const float2*)&qs[qi * 66 + h * 16 + d2];
    float sc[16];
    #pragma unroll
    for (int jj = 0; jj < 16; ++jj) {
        int j = half * 16 + jj;
        const float* kr = &ks[j * 64 + h * 16];
        float a = 0.f;
        #pragma unroll
        for (int d4 = 0; d4 < 16; d4 += 4) {
            float4 kv = *(const float4*)&kr[d4];
            a += qreg[d4] * kv.x + qreg[d4 + 1] * kv.y + qreg[d4 + 2] * kv.z + qreg[d4 + 3] * kv.w;
        }
        sc[jj] = a;
    }
    float mx = sc[0];
    #pragma unroll
    for (int jj = 1; jj < 16; ++jj) mx = fmaxf(mx, sc[jj]);
    mx = fmaxf(mx, __shfl_xor(mx, 1));
    float sum = 0.f;
    #pragma unroll
    for (int jj = 0; jj < 16; ++jj) { sc[jj] = __expf(sc[jj] - mx); sum += sc[jj]; }
    sum += __shfl_xor(sum, 1);
    float inv = 1.0f / sum;
    __syncthreads();
    #pragma unroll
    for (int jj = 0; jj < 16; ++jj)
        psT[(half * 16 + jj) * 128 + h * 32 + qi] = sc[jj] * inv;
    __syncthreads();

    int si = tid >> 3, e0 = (tid & 7) * 8;
    int hh = e0 >> 4;
    float oacc[8] = {};
    for (int j = 0; j < 32; ++j) {
        float pj = psT[j * 128 + hh * 32 + si];
        const float* vr = &vs[j * 64 + e0];
        float4 v0 = *(const float4*)&vr[0];
        float4 v1 = *(const float4*)&vr[4];
        oacc[0] += pj * v0.x; oacc[1] += pj * v0.y; oacc[2] += pj * v0.z; oacc[3] += pj * v0.w;
        oacc[4] += pj * v1.x; oacc[5] += pj * v1.y; oacc[6] += pj * v1.z; oacc[7] += pj * v1.w;
    }
    #pragma unroll
    for (int e = 0; e < 8; ++e) os[si * 68 + e0 + e] = oacc[e];
    __syncthreads();

    int r8 = tid & 7;
    float z[8];
    {
        float accq[8];
        #pragma unroll
        for (int q = 0; q < 8; ++q) accq[q] = bos[r8 + q * 8];
        #pragma unroll 4
        for (int e4 = 0; e4 < 64; e4 += 4) {
            float4 ov = *(const float4*)&os[si * 68 + e4];
            #pragma unroll
            for (int q = 0; q < 8; ++q) {
                float4 wv = *(const float4*)&wos[(r8 + q * 8) * 68 + e4];
                accq[q] += ov.x * wv.x + ov.y * wv.y + ov.z * wv.z + ov.w * wv.w;
            }
        }
        long ubase = (((long)g * 32 + si) * 256 + b) * 64;
        #pragma unroll
        for (int q = 0; q < 8; ++q) z[q] = accq[q] + u[ubase + r8 + q * 8];
    }
    float s1 = 0.f, s2 = 0.f;
    #pragma unroll
    for (int q = 0; q < 8; ++q) { s1 += z[q]; s2 += z[q] * z[q]; }
    #pragma unroll
    for (int off = 1; off < 8; off <<= 1) { s1 += __shfl_xor(s1, off); s2 += __shfl_xor(s2, off); }
    float mu = s1 * 0.015625f;
    float var = s2 * 0.015625f - mu * mu;
    float rstd = rsqrtf(var + EPS);
    long obase = (((long)g * 32 + si) * 256 + b) * 64;
    #pragma unroll
    for (int q = 0; q < 8; ++q) {
        int e2 = r8 + q * 8;
        out[obase + e2] = f2bf((z[q] - mu) * rstd * lws[e2] + lbs[e2]);
    }
}

// ===========================================================================
// Encoder attention (L=16, h=16, hd=128). bf16 in, bf16 out.
// ===========================================================================
__global__ __launch_bounds__(256) void enc_att(
    const ushort* __restrict__ qkv, ushort* __restrict__ o)
{
    __shared__ float qs[16 * 132], ks[16 * 132], vs[16 * 132], ps[16 * 17];
    int bh = blockIdx.x;
    int b2 = bh >> 4, h = bh & 15;
    int tid = threadIdx.x;
    const float qscale = 0.08838834764831845f;  // 128^-0.5
    {
        int e = tid;                 // 256 units of 8 elems = 16 rows x 128 cols
        int l = e >> 4, c8 = (e & 15) * 8;
        long rowoff = ((long)l * 256 + b2) * 6144 + h * 128 + c8;
        union { s16x8 v8; ushort us[8]; } q, k, v;
        q.v8 = *(const s16x8*)(qkv + rowoff);
        k.v8 = *(const s16x8*)(qkv + rowoff + 2048);
        v.v8 = *(const s16x8*)(qkv + rowoff + 4096);
        #pragma unroll
        for (int j = 0; j < 8; ++j) {
            qs[l * 132 + c8 + j] = bf2f(q.us[j]) * qscale;
            ks[l * 132 + c8 + j] = bf2f(k.us[j]);
            vs[l * 132 + c8 + j] = bf2f(v.us[j]);
        }
    }
    __syncthreads();
    int qi = tid >> 4, j = tid & 15;
    float acc = 0.f;
    #pragma unroll
    for (int d = 0; d < 128; d += 4) {
        float4 qv = *(const float4*)&qs[qi * 132 + d];
        float4 kv = *(const float4*)&ks[j * 132 + d];
        acc += qv.x * kv.x + qv.y * kv.y + qv.z * kv.z + qv.w * kv.w;
    }
    float m = acc;
    #pragma unroll
    for (int off = 1; off < 16; off <<= 1) m = fmaxf(m, __shfl_xor(m, off));
    float p = __expf(acc - m);
    float sum = p;
    #pragma unroll
    for (int off = 1; off < 16; off <<= 1) sum += __shfl_xor(sum, off);
    ps[qi * 17 + j] = p / sum;
    __syncthreads();
    float pr[16];
    #pragma unroll
    for (int jj = 0; jj < 16; ++jj) pr[jj] = ps[qi * 17 + jj];
    long obase = ((long)qi * 256 + b2) * 2048 + h * 128;
    #pragma unroll
    for (int qd = 0; qd < 8; ++qd) {
        int d = (tid & 15) + qd * 16;
        float a = 0.f;
        #pragma unroll
        for (int jj = 0; jj < 16; ++jj) a += pr[jj] * vs[jj * 132 + d];
        o[obase + d] = f2bf(a);
    }
}

// ===========================================================================
// residual + LayerNorm over 2048.  RSD_BF: bf16 residual.
// OUT_BF: 0 = fp32 only, 1 = fp32 + bf16, 2 = bf16 only.
// ===========================================================================
template <int RSD_BF, int OUT_BF>
__global__ __launch_bounds__(256) void resid_ln(
    const float* __restrict__ y, const void* __restrict__ rsdv,
    const float* __restrict__ w, const float* __restrict__ bb,
    float* __restrict__ out, ushort* __restrict__ outb)
{
    __shared__ float red[8];
    int tid = threadIdx.x;
    long row = blockIdx.x;
    const float* yr = y + row * 2048;
    float4 a0 = *(const float4*)(yr + tid * 4);
    float4 a1 = *(const float4*)(yr + 1024 + tid * 4);
    float r[8];
    if (RSD_BF) {
        const ushort* rr = (const ushort*)rsdv + row * 2048;
        ushort4 u0 = *(const ushort4*)(rr + tid * 4);
        ushort4 u1 = *(const ushort4*)(rr + 1024 + tid * 4);
        r[0] = bf2f(u0.x); r[1] = bf2f(u0.y); r[2] = bf2f(u0.z); r[3] = bf2f(u0.w);
        r[4] = bf2f(u1.x); r[5] = bf2f(u1.y); r[6] = bf2f(u1.z); r[7] = bf2f(u1.w);
    } else {
        const float* rr = (const float*)rsdv + row * 2048;
        float4 r0 = *(const float4*)(rr + tid * 4);
        float4 r1 = *(const float4*)(rr + 1024 + tid * 4);
        r[0] = r0.x; r[1] = r0.y; r[2] = r0.z; r[3] = r0.w;
        r[4] = r1.x; r[5] = r1.y; r[6] = r1.z; r[7] = r1.w;
    }
    float v[8] = { a0.x + r[0], a0.y + r[1], a0.z + r[2], a0.w + r[3],
                   a1.x + r[4], a1.y + r[5], a1.z + r[6], a1.w + r[7] };
    float s1 = 0.f, s2 = 0.f;
    #pragma unroll
    for (int i = 0; i < 8; ++i) { s1 += v[i]; s2 += v[i] * v[i]; }
    #pragma unroll
    for (int off = 1; off < 64; off <<= 1) { s1 += __shfl_xor(s1, off); s2 += __shfl_xor(s2, off); }
    int wid = tid >> 6, lane = tid & 63;
    if (lane == 0) { red[wid * 2] = s1; red[wid * 2 + 1] = s2; }
    __syncthreads();
    s1 = red[0] + red[2] + red[4] + red[6];
    s2 = red[1] + red[3] + red[5] + red[7];
    float mu = s1 * (1.0f / 2048.0f);
    float var = s2 * (1.0f / 2048.0f) - mu * mu;
    float rstd = rsqrtf(var + EPS);
    float4 w0 = *(const float4*)(w + tid * 4);
    float4 w1 = *(const float4*)(w + 1024 + tid * 4);
    float4 b0 = *(const float4*)(bb + tid * 4);
    float4 b1 = *(const float4*)(bb + 1024 + tid * 4);
    float o0[8];
    o0[0] = (v[0] - mu) * rstd * w0.x + b0.x; o0[1] = (v[1] - mu) * rstd * w0.y + b0.y;
    o0[2] = (v[2] - mu) * rstd * w0.z + b0.z; o0[3] = (v[3] - mu) * rstd * w0.w + b0.w;
    o0[4] = (v[4] - mu) * rstd * w1.x + b1.x; o0[5] = (v[5] - mu) * rstd * w1.y + b1.y;
    o0[6] = (v[6] - mu) * rstd * w1.z + b1.z; o0[7] = (v[7] - mu) * rstd * w1.w + b1.w;
    if (OUT_BF != 2) {
        *(float4*)(out + row * 2048 + tid * 4) = *(float4*)&o0[0];
        *(float4*)(out + row * 2048 + 1024 + tid * 4) = *(float4*)&o0[4];
    }
    if (OUT_BF) {
        ushort4 q0, q1;
        q0.x = f2bf(o0[0]); q0.y = f2bf(o0[1]); q0.z = f2bf(o0[2]); q0.w = f2bf(o0[3]);
        q1.x = f2bf(o0[4]); q1.y = f2bf(o0[5]); q1.z = f2bf(o0[6]); q1.w = f2bf(o0[7]);
        *(ushort4*)(outb + row * 2048 + tid * 4) = q0;
        *(ushort4*)(outb + row * 2048 + 1024 + tid * 4) = q1;
    }
}

// ===========================================================================
extern "C" void kernel_launch(void* const* d_in, const int* in_sizes, int n_in,
                              void* d_out, int out_size, void* d_ws, size_t ws_size,
                              hipStream_t stream)
{
    (void)in_sizes; (void)n_in; (void)out_size; (void)ws_size;
    const float* t        = (const float*)d_in[0];
    const float* conv1_w  = (const float*)d_in[1];
    const float* conv1_b  = (const float*)d_in[2];
    const float* conv2_w  = (const float*)d_in[3];
    const float* conv2_b  = (const float*)d_in[4];
    const float* expand_w = (const float*)d_in[5];
    const float* expand_b = (const float*)d_in[6];
    const float* mha_wqkv = (const float*)d_in[7];
    const float* mha_bqkv = (const float*)d_in[8];
    const float* mha_wo   = (const float*)d_in[9];
    const float* mha_bo   = (const float*)d_in[10];
    const float* ln1_w    = (const float*)d_in[11];
    const float* ln1_b    = (const float*)d_in[12];
    const float* enc_wqkv = (const float*)d_in[13];
    const float* enc_bqkv = (const float*)d_in[14];
    const float* enc_wo   = (const float*)d_in[15];
    const float* enc_bo   = (const float*)d_in[16];
    const float* enc_ln1w = (const float*)d_in[17];
    const float* enc_ln1b = (const float*)d_in[18];
    const float* enc_w1   = (const float*)d_in[19];
    const float* enc_b1   = (const float*)d_in[20];
    const float* enc_w2   = (const float*)d_in[21];
    const float* enc_b2   = (const float*)d_in[22];
    const float* enc_ln2w = (const float*)d_in[23];
    const float* enc_ln2b = (const float*)d_in[24];
    const float* f1_w     = (const float*)d_in[25];
    const float* f1_b     = (const float*)d_in[26];
    const float* f2_w     = (const float*)d_in[27];
    const float* f2_b     = (const float*)d_in[28];
    const float* f3_w     = (const float*)d_in[29];
    const float* f3_b     = (const float*)d_in[30];
    float* out = (float*)d_out;

    float* W = (float*)d_ws;
    // ---- region plan (float offsets), lifetimes verified stage-by-stage: ----
    ushort* u1b    = (ushort*)W;               // [0,14745600)        c1->c2
    float*  u2     = W + 29491200;             // [29491200,34209792) c2->ex
    float*  u      = W + 34209792;             // [34209792,42598400) ex->gatt (residual)
    ushort* u_b    = (ushort*)(W + 12582912);  // [12582912,16777216) ex->gqkv (u1b dead rows? no: u1b ends 14745600 — overlap!)
    // NOTE: u1b [0,14745600) is dead only after conv2. u_b written by expand
    // (after conv2) at [12582912,16777216): overlaps u1b tail — u1b dead ✓.
    ushort* qkvg_b = (ushort*)W;               // [0,12582912)        gqkv->gatt (u1b dead)
    ushort* wqg_b  = (ushort*)(W + 46804608);  // [46804608,46902912) mha_wqkv bf16
    ushort* uln_b  = (ushort*)(W + 42598400);  // [42598400,46792704) gatt->ln1
    ushort* wk     = (ushort*)(W + 46800000);  // [46800000,46804608) prep->conv2
    ushort* wqkv_b = (ushort*)(W + 12582912);  // [12582912,18874368) enc qkv w (u_b,qkvg dead after gatt... u_b dead after gqkv ✓)
    ushort* wo_b   = (ushort*)(W + 18874368);  // [18874368,20971520)
    ushort* w1_b   = (ushort*)(W + 20971520);  // [20971520,23068672)
    ushort* w2_b   = (ushort*)(W + 23068672);  // [23068672,25165824)
    ushort* qkv2_b = (ushort*)W;               // [0,12582912)        qkvgemm->encatt (qkvg_b dead)
    ushort* obuf_b = (ushort*)(W + 25165824);  // [25165824,29360128) encatt->oproj
    float*  ytmp   = W + 29360128;             // [29360128,37748736) oproj->ln1, ffn2->ln2 (u2/u dead)
    float*  x1     = W;                        // [0,8388608)         ln1->ln2 (qkv2_b dead)
    ushort* x1_b   = (ushort*)(W + 8388608);   // [8388608,12582912)  ln1->ffn1
    ushort* hbuf_b = (ushort*)(W + 37748736);  // [37748736,41943040) ffn1->ffn2
    ushort* x2_b   = (ushort*)(W + 20971520);  // [20971520,25165824) ln2->f1 (w1_b/w2_b dead)
    ushort* f1w_b  = (ushort*)W;               // [0,8388608)         f2b->f1 (x1 dead after ln2)
    float*  f1part = W + 29360128;             // [29360128,37748736) f1->reduce (ytmp dead)
    float*  f1o    = W + 25165824;             // [25165824,25296896) reduce->f2 (obuf dead)
    float*  f2o    = W + 25296896;             // [25296896,25329664)

    dim3 blk(256);
    convw_prep<<<36, blk, 0, stream>>>(conv2_w, wk);
    f2b_kernel<<<96, blk, 0, stream>>>(mha_wqkv, wqg_b, 24576);
    conv1_pool<<<4096, blk, 0, stream>>>(t, conv1_w, conv1_b, u1b);
    conv2_mfma<<<2048, blk, 0, stream>>>(u1b, wk, conv2_b, u2);
    expand_k<<<2048, blk, 0, stream>>>(u2, expand_w, expand_b, u, u_b);
    // grouped qkv (bf16 MFMA): per g (8192,64)@(64,192)^T -> bf16
    gqkv_mfma<<<dim3(64, 16), blk, 0, stream>>>(u_b, wqg_b, mha_bqkv, qkvg_b);
    gatt_ln<<<4096, blk, 0, stream>>>(qkvg_b, u, mha_wo, mha_bo, ln1_w, ln1_b, uln_b);
    // enc weight conversions (qkvg_b/u_b regions dead now)
    f2b_kernel<<<6144, blk, 0, stream>>>(enc_wqkv, wqkv_b, 1572864);
    f2b_kernel<<<2048, blk, 0, stream>>>(enc_wo, wo_b, 524288);
    f2b_kernel<<<2048, blk, 0, stream>>>(enc_w1, w1_b, 524288);
    f2b_kernel<<<2048, blk, 0, stream>>>(enc_w2, w2_b, 524288);
    // encoder qkv (bf16 MFMA): (4096,2048)@(2048,6144)^T -> bf16
    gemm_bf16<0, 2><<<dim3(48, 32), blk, 0, stream>>>(
        uln_b, wqkv_b, enc_bqkv, nullptr, qkv2_b, 4096, 6144, 2048);
    enc_att<<<4096, blk, 0, stream>>>(qkv2_b, obuf_b);
    // o-proj (bf16 MFMA) -> fp32
    gemm_bf16<0, 0><<<dim3(16, 32), blk, 0, stream>>>(
        obuf_b, wo_b, enc_bo, ytmp, nullptr, 4096, 2048, 2048);
    resid_ln<1, 1><<<4096, blk, 0, stream>>>(ytmp, uln_b, enc_ln1w, enc_ln1b, x1, x1_b);
    // FFN1 (bf16 MFMA, relu, bf16 out)
    gemm_bf16<1, 2><<<dim3(16, 32), blk, 0, stream>>>(
        x1_b, w1_b, enc_b1, nullptr, hbuf_b, 4096, 2048, 2048);
    // FFN2 (bf16 MFMA) -> fp32
    gemm_bf16<0, 0><<<dim3(16, 32), blk, 0, stream>>>(
        hbuf_b, w2_b, enc_b2, ytmp, nullptr, 4096, 2048, 2048);
    // ln2: bf16 only
    resid_ln<0, 2><<<4096, blk, 0, stream>>>(ytmp, x1, enc_ln2w, enc_ln2b, nullptr, x2_b);
    // f1 (bf16 MFMA, split-K=64, partials + reduce; no atomics)
    f2b_kernel<<<8192, blk, 0, stream>>>(f1_w, f1w_b, 2097152);
    gemm_bf16<0, 0, 64><<<dim3(4, 2, 64), blk, 0, stream>>>(
        x2_b, f1w_b, nullptr, f1part, nullptr, 256, 512, 32768);
    f1_reduce<<<512, blk, 0, stream>>>(f1part, f1_b, f1o);
    // f2: (256,512)@(512,128)^T + relu (fp32)
    gemm_tn<64, 64, 16, 4, 4, 1, 1><<<dim3(2, 4, 1), blk, 0, stream>>>(
        f1o, f2_w, f2_b, f2o, 256, 128, 512, 512, 512, 128, 0, 0, 0, 0);
    // f3: (256,128)@(128,25)^T -> d_out (fp32)
    gemm_tn<64, 64, 16, 4, 4, 0, 1><<<dim3(1, 4, 1), blk, 0, stream>>>(
        f2o, f3_w, f3_b, out, 256, 25, 128, 128, 128, 25, 0, 0, 0, 0);
}